// Round 2
// baseline (1883.552 us; speedup 1.0000x reference)
//
#include <hip/hip_runtime.h>
#include <hip/hip_bf16.h>

// Problem constants
constexpr int B = 4, L = 2048, E = 300, D = 128, NH = 4, HD = 128, NL = 3, D2 = 512;
constexpr int L1 = L + 1; // 2049
constexpr float EPS = 1e-5f;
constexpr float SCALE = 0.08838834764831843f; // 1/sqrt(128)

// ---------------- embedding gather + projection: x = emb[tok] @ proj_w.T + proj_b
__global__ __launch_bounds__(128) void embed_proj_kernel(
    const int* __restrict__ tokens, const float* __restrict__ emb,
    const float* __restrict__ pw, const float* __restrict__ pb,
    float* __restrict__ x, float* __restrict__ nodes) {
  __shared__ float es[E];
  int bl = blockIdx.x, t = threadIdx.x;
  int tok = tokens[bl];
  const float2* e2 = (const float2*)(emb + (size_t)tok * E);
  for (int i = t; i < E / 2; i += 128) { float2 f = e2[i]; es[2 * i] = f.x; es[2 * i + 1] = f.y; }
  __syncthreads();
  float acc = pb[t];
  const float2* w2 = (const float2*)(pw + (size_t)t * E);
  for (int i = 0; i < E / 2; i++) { float2 wv = w2[i]; acc += es[2 * i] * wv.x + es[2 * i + 1] * wv.y; }
  x[(size_t)bl * D + t] = acc;
  nodes[(size_t)bl * D + t] = acc;
}

// ---------------- relay = mean over L of x  (relay must be zeroed first)
__global__ __launch_bounds__(128) void relay_init_kernel(const float* __restrict__ x, float* __restrict__ relay) {
  int b = blockIdx.x >> 4, c = blockIdx.x & 15, t = threadIdx.x;
  float sum = 0.f;
  for (int i = 0; i < 128; i++) {
    int l = c * 128 + i;
    sum += x[((size_t)b * L + l) * D + t];
  }
  atomicAdd(&relay[b * D + t], sum * (1.0f / L));
}

// ---------------- layernorm row kernel (D=128, 128 threads)
__global__ __launch_bounds__(128) void ln_kernel(
    const float* __restrict__ in, float* __restrict__ out,
    const float* __restrict__ g, const float* __restrict__ bb) {
  int row = blockIdx.x, t = threadIdx.x;
  float v = in[(size_t)row * D + t];
  float s = v, s2 = v * v;
#pragma unroll
  for (int o = 1; o < 64; o <<= 1) { s += __shfl_xor(s, o, 64); s2 += __shfl_xor(s2, o, 64); }
  __shared__ float rs[2], rs2[2];
  int w = t >> 6;
  if ((t & 63) == 0) { rs[w] = s; rs2[w] = s2; }
  __syncthreads();
  float S = rs[0] + rs[1], S2 = rs2[0] + rs2[1];
  float mu = S * (1.0f / D);
  float var = S2 * (1.0f / D) - mu * mu;
  float r = rsqrtf(var + EPS);
  out[(size_t)row * D + t] = (v - mu) * r * g[t] + bb[t];
}

// ---------------- generic GEMM: out[M,N] = A[M,K] @ W[N,K]^T + bias
// relayrows: out_row = row + row/L + 1 (for sk/sv packed as [B, L+1, D2])
// residleaky: out = resid + leaky_relu(acc + bias)
__global__ __launch_bounds__(256) void gemm_kernel(
    const float* __restrict__ A, const float* __restrict__ W,
    const float* __restrict__ bias, float* __restrict__ out,
    const float* __restrict__ resid, int M, int N, int K,
    int relayrows, int residleaky) {
  __shared__ float As[64][36];
  __shared__ float Ws[64][36];
  int tid = threadIdx.x;
  int bm = blockIdx.x, bn = blockIdx.y;
  int tx = tid & 15, ty = tid >> 4;
  float acc[4][4] = {};
  const int rowA = bm * 64, rowW = bn * 64;
  for (int kt = 0; kt < K; kt += 32) {
#pragma unroll
    for (int i = 0; i < 8; i++) {
      int lin = tid + (i << 8);
      int r = lin >> 5, c = lin & 31;
      As[r][c] = A[(size_t)(rowA + r) * K + kt + c];
      Ws[r][c] = W[(size_t)(rowW + r) * K + kt + c];
    }
    __syncthreads();
#pragma unroll
    for (int kk = 0; kk < 32; kk += 4) {
      float4 av[4], bv[4];
#pragma unroll
      for (int i = 0; i < 4; i++) {
        av[i] = *(const float4*)&As[ty * 4 + i][kk];
        bv[i] = *(const float4*)&Ws[tx * 4 + i][kk];
      }
#pragma unroll
      for (int i = 0; i < 4; i++)
#pragma unroll
        for (int j = 0; j < 4; j++)
          acc[i][j] += av[i].x * bv[j].x + av[i].y * bv[j].y + av[i].z * bv[j].z + av[i].w * bv[j].w;
    }
    __syncthreads();
  }
#pragma unroll
  for (int i = 0; i < 4; i++) {
    int row = rowA + ty * 4 + i;
    int orow = relayrows ? (row + row / L + 1) : row;
#pragma unroll
    for (int j = 0; j < 4; j++) {
      int col = rowW + tx * 4 + j;
      float v = acc[i][j] + bias[col];
      if (residleaky) {
        v = (v > 0.f) ? v : 0.01f * v;
        v += resid[(size_t)row * N + col];
      }
      out[(size_t)orow * N + col] = v;
    }
  }
}

// ---------------- small matvec for relay-row projections: out[b, n] = A[b,:K] @ W[n,:K] + bias[n]
__global__ __launch_bounds__(128) void matvec_kernel(
    const float* __restrict__ A, const float* __restrict__ W, const float* __restrict__ bias,
    float* __restrict__ out, int K, int N, int outStride, int leaky) {
  __shared__ float as[512];
  int b = blockIdx.x;
  int n = blockIdx.y * 128 + threadIdx.x;
  for (int i = threadIdx.x; i < K; i += 128) as[i] = A[(size_t)b * K + i];
  __syncthreads();
  float acc = bias[n];
  const float2* w2 = (const float2*)(W + (size_t)n * K);
  for (int i = 0; i < K / 2; i++) { float2 wv = w2[i]; acc += as[2 * i] * wv.x + as[2 * i + 1] * wv.y; }
  if (leaky) acc = (acc > 0.f) ? acc : 0.01f * acc;
  out[(size_t)b * outStride + n] = acc;
}

// ---------------- ring (windowed) attention, 5 kv entries per (b,l,head)
__global__ __launch_bounds__(256) void ring_attn_kernel(
    const float* __restrict__ q, const float* __restrict__ k, const float* __restrict__ v,
    const float* __restrict__ akr, const float* __restrict__ avr,
    const float* __restrict__ rk, const float* __restrict__ rv,
    float* __restrict__ att) {
  int bl = blockIdx.x;
  int b = bl >> 11, l = bl & (L - 1);
  int n = threadIdx.x >> 6, lane = threadIdx.x & 63;
  int h = lane << 1;
  size_t base = (size_t)bl * D2 + n * HD + h;
  float q0 = q[base], q1 = q[base + 1];
  float s[5], v0[5], v1[5];
#pragma unroll
  for (int u = 0; u < 5; u++) {
    float k0 = 0.f, k1 = 0.f, vv0 = 0.f, vv1 = 0.f;
    if (u < 3) {
      int ll = l + u - 1;
      if (ll >= 0 && ll < L) {
        size_t off = ((size_t)b * L + ll) * D2 + n * HD + h;
        k0 = k[off]; k1 = k[off + 1]; vv0 = v[off]; vv1 = v[off + 1];
      }
    } else if (u == 3) {
      k0 = akr[base]; k1 = akr[base + 1]; vv0 = avr[base]; vv1 = avr[base + 1];
    } else {
      size_t rb = (size_t)b * D2 + n * HD + h;
      k0 = rk[rb]; k1 = rk[rb + 1]; vv0 = rv[rb]; vv1 = rv[rb + 1];
    }
    float p = q0 * k0 + q1 * k1;
#pragma unroll
    for (int o = 1; o < 64; o <<= 1) p += __shfl_xor(p, o, 64);
    s[u] = p * SCALE;
    v0[u] = vv0; v1[u] = vv1;
  }
  float m = s[0];
#pragma unroll
  for (int u = 1; u < 5; u++) m = fmaxf(m, s[u]);
  float sum = 0.f, o0 = 0.f, o1 = 0.f;
#pragma unroll
  for (int u = 0; u < 5; u++) {
    float e = expf(s[u] - m);
    sum += e; o0 += e * v0[u]; o1 += e * v1[u];
  }
  att[base] = o0 / sum;
  att[base + 1] = o1 / sum;
}

// ---------------- relay (global) attention over L+1 positions per (b, head)
__global__ __launch_bounds__(256) void relay_attn_kernel(
    const float* __restrict__ sq, const float* __restrict__ sk, const float* __restrict__ sv,
    const int* __restrict__ mask, float* __restrict__ satt) {
  int b = blockIdx.x >> 2, n = blockIdx.x & 3;
  __shared__ float sc[L1];
  __shared__ float sqs[HD];
  __shared__ float red[4];
  int t = threadIdx.x;
  if (t < HD) sqs[t] = sq[(size_t)b * D2 + n * HD + t];
  __syncthreads();
  for (int l = t; l < L1; l += 256) {
    const float4* kp = (const float4*)(sk + ((size_t)b * L1 + l) * D2 + n * HD);
    const float4* qp = (const float4*)sqs;
    float s = 0.f;
#pragma unroll 4
    for (int hh = 0; hh < HD / 4; hh++) {
      float4 a = qp[hh], c = kp[hh];
      s += a.x * c.x + a.y * c.y + a.z * c.z + a.w * c.w;
    }
    s *= SCALE;
    if (l > 0 && mask[b * L + l - 1] == 0) s = -1e30f;
    sc[l] = s;
  }
  __syncthreads();
  float m = -1e30f;
  for (int l = t; l < L1; l += 256) m = fmaxf(m, sc[l]);
#pragma unroll
  for (int o = 1; o < 64; o <<= 1) m = fmaxf(m, __shfl_xor(m, o, 64));
  if ((t & 63) == 0) red[t >> 6] = m;
  __syncthreads();
  m = fmaxf(fmaxf(red[0], red[1]), fmaxf(red[2], red[3]));
  float sum = 0.f;
  for (int l = t; l < L1; l += 256) { float e = expf(sc[l] - m); sc[l] = e; sum += e; }
#pragma unroll
  for (int o = 1; o < 64; o <<= 1) sum += __shfl_xor(sum, o, 64);
  __syncthreads();
  if ((t & 63) == 0) red[t >> 6] = sum;
  __syncthreads();
  sum = red[0] + red[1] + red[2] + red[3];
  if (t < HD) {
    float o = 0.f;
    for (int l = 0; l < L1; l++) o += sc[l] * sv[((size_t)b * L1 + l) * D2 + n * HD + t];
    satt[(size_t)b * D2 + n * HD + t] = o / sum;
  }
}

// ---------------- zero nodes at padded positions
__global__ __launch_bounds__(256) void mask_nodes_kernel(float* __restrict__ nodes, const int* __restrict__ mask) {
  int idx = blockIdx.x * 256 + threadIdx.x;
  int bl = idx >> 7;
  if (mask[bl] == 0) nodes[idx] = 0.f;
}

extern "C" void kernel_launch(void* const* d_in, const int* in_sizes, int n_in,
                              void* d_out, int out_size, void* d_ws, size_t ws_size,
                              hipStream_t stream) {
  const int* tokens = (const int*)d_in[0];
  const int* mask = (const int*)d_in[1];
  const float* emb = (const float*)d_in[2];
  const float* proj_w = (const float*)d_in[3];
  const float* proj_b = (const float*)d_in[4];
  const float* ng = (const float*)d_in[5];
  const float* nb = (const float*)d_in[6];
  const float* rq_w = (const float*)d_in[7], * rq_b = (const float*)d_in[8];
  const float* rk_w = (const float*)d_in[9], * rk_b = (const float*)d_in[10];
  const float* rv_w = (const float*)d_in[11], * rv_b = (const float*)d_in[12];
  const float* ro_w = (const float*)d_in[13], * ro_b = (const float*)d_in[14];
  const float* sq_w = (const float*)d_in[15], * sq_b = (const float*)d_in[16];
  const float* sk_w = (const float*)d_in[17], * sk_b = (const float*)d_in[18];
  const float* sv_w = (const float*)d_in[19], * sv_b = (const float*)d_in[20];
  const float* so_w = (const float*)d_in[21], * so_b = (const float*)d_in[22];

  float* ws = (float*)d_ws;
  const size_t BLD = (size_t)B * L * D;       // 1,048,576
  const size_t SLOT = (size_t)B * L1 * D2;    // 4,196,352
  float* x = ws;
  float* nodes = x + BLD;
  float* nx = nodes + BLD;
  float* relay = nx + BLD;
  float* relay_k = relay + B * D;
  float* relay_v = relay_k + B * D2;
  float* sqv = relay_v + B * D2;
  float* satt = sqv + B * D2;
  float* slot0 = satt + B * D2;   // q, later sk
  float* slot1 = slot0 + SLOT;    // k, later sv
  float* slot2 = slot1 + SLOT;    // v
  float* slot3 = slot2 + SLOT;    // ak (r_embs)
  float* slot4 = slot3 + SLOT;    // av (r_embs)
  float* slot5 = slot4 + SLOT;    // att
  // total ~113.3 MB of fp32 scratch

  hipMemsetAsync(relay, 0, B * D * sizeof(float), stream);
  embed_proj_kernel<<<B * L, 128, 0, stream>>>(tokens, emb, proj_w, proj_b, x, nodes);
  relay_init_kernel<<<B * 16, 128, 0, stream>>>(x, relay);

  const dim3 g8(128, 8), g2(128, 2);
  for (int i = 0; i < NL; i++) {
    const float* rqwi = rq_w + (size_t)i * D2 * D, * rqbi = rq_b + (size_t)i * D2;
    const float* rkwi = rk_w + (size_t)i * D2 * D, * rkbi = rk_b + (size_t)i * D2;
    const float* rvwi = rv_w + (size_t)i * D2 * D, * rvbi = rv_b + (size_t)i * D2;
    const float* rowi = ro_w + (size_t)i * D * D2, * robi = ro_b + (size_t)i * D;
    const float* sqwi = sq_w + (size_t)i * D2 * D, * sqbi = sq_b + (size_t)i * D2;
    const float* skwi = sk_w + (size_t)i * D2 * D, * skbi = sk_b + (size_t)i * D2;
    const float* svwi = sv_w + (size_t)i * D2 * D, * svbi = sv_b + (size_t)i * D2;
    const float* sowi = so_w + (size_t)i * D * D2, * sobi = so_b + (size_t)i * D;

    ln_kernel<<<B * L, 128, 0, stream>>>(nodes, nx, ng + i * D, nb + i * D);
    // q, k, v from nx; ak, av from original embeddings x
    gemm_kernel<<<g8, 256, 0, stream>>>(nx, rqwi, rqbi, slot0, nullptr, B * L, D2, D, 0, 0);
    gemm_kernel<<<g8, 256, 0, stream>>>(nx, rkwi, rkbi, slot1, nullptr, B * L, D2, D, 0, 0);
    gemm_kernel<<<g8, 256, 0, stream>>>(nx, rvwi, rvbi, slot2, nullptr, B * L, D2, D, 0, 0);
    gemm_kernel<<<g8, 256, 0, stream>>>(x, rkwi, rkbi, slot3, nullptr, B * L, D2, D, 0, 0);
    gemm_kernel<<<g8, 256, 0, stream>>>(x, rvwi, rvbi, slot4, nullptr, B * L, D2, D, 0, 0);
    // relay entries of ring attention (from layer-entry relay)
    matvec_kernel<<<dim3(B, 4), 128, 0, stream>>>(relay, rkwi, rkbi, relay_k, D, D2, D2, 0);
    matvec_kernel<<<dim3(B, 4), 128, 0, stream>>>(relay, rvwi, rvbi, relay_v, D, D2, D2, 0);
    ring_attn_kernel<<<B * L, 256, 0, stream>>>(slot0, slot1, slot2, slot3, slot4, relay_k, relay_v, slot5);
    // nodes += leaky_relu(att @ ro_w.T + ro_b)
    gemm_kernel<<<g2, 256, 0, stream>>>(slot5, rowi, robi, nodes, nodes, B * L, D, D2, 0, 1);
    // MSA2
    matvec_kernel<<<dim3(B, 4), 128, 0, stream>>>(relay, sqwi, sqbi, sqv, D, D2, D2, 0);
    gemm_kernel<<<g8, 256, 0, stream>>>(nodes, skwi, skbi, slot0, nullptr, B * L, D2, D, 1, 0);
    matvec_kernel<<<dim3(B, 4), 128, 0, stream>>>(relay, skwi, skbi, slot0, D, D2, L1 * D2, 0);
    gemm_kernel<<<g8, 256, 0, stream>>>(nodes, svwi, svbi, slot1, nullptr, B * L, D2, D, 1, 0);
    matvec_kernel<<<dim3(B, 4), 128, 0, stream>>>(relay, svwi, svbi, slot1, D, D2, L1 * D2, 0);
    relay_attn_kernel<<<B * NH, 256, 0, stream>>>(sqv, slot0, slot1, mask, satt);
    // relay = leaky_relu(satt @ so_w.T + so_b); last layer writes d_out directly
    float* relay_dst = (i == NL - 1) ? (float*)d_out : relay;
    matvec_kernel<<<dim3(B, 1), 128, 0, stream>>>(satt, sowi, sobi, relay_dst, D2, D, D, 1);
    // nodes = where(pad, 0, nodes)
    mask_nodes_kernel<<<(B * L * D) / 256, 256, 0, stream>>>(nodes, mask);
  }
}

// Round 3
// 1269.940 us; speedup vs baseline: 1.4832x; 1.4832x over previous
//
#include <hip/hip_runtime.h>
#include <hip/hip_bf16.h>

// Problem constants
constexpr int B = 4, L = 2048, E = 300, D = 128, NH = 4, HD = 128, NL = 3, D2 = 512;
constexpr int L1 = L + 1; // 2049
constexpr float EPS = 1e-5f;
constexpr float SCALE = 0.08838834764831843f; // 1/sqrt(128)
constexpr int NCH = 32;              // relay-attention L-chunks
constexpr int CHUNK = 65;            // ceil(2049/32)

// ---------------- embedding gather + projection: x = emb[tok] @ proj_w.T + proj_b
__global__ __launch_bounds__(128) void embed_proj_kernel(
    const int* __restrict__ tokens, const float* __restrict__ emb,
    const float* __restrict__ pw, const float* __restrict__ pb,
    float* __restrict__ x, float* __restrict__ nodes) {
  __shared__ float es[E];
  int bl = blockIdx.x, t = threadIdx.x;
  int tok = tokens[bl];
  const float2* e2 = (const float2*)(emb + (size_t)tok * E);
  for (int i = t; i < E / 2; i += 128) { float2 f = e2[i]; es[2 * i] = f.x; es[2 * i + 1] = f.y; }
  __syncthreads();
  float acc = pb[t];
  const float2* w2 = (const float2*)(pw + (size_t)t * E);
  for (int i = 0; i < E / 2; i++) { float2 wv = w2[i]; acc += es[2 * i] * wv.x + es[2 * i + 1] * wv.y; }
  x[(size_t)bl * D + t] = acc;
  nodes[(size_t)bl * D + t] = acc;
}

// ---------------- relay = mean over L of x  (relay must be zeroed first)
__global__ __launch_bounds__(128) void relay_init_kernel(const float* __restrict__ x, float* __restrict__ relay) {
  int b = blockIdx.x >> 4, c = blockIdx.x & 15, t = threadIdx.x;
  float sum = 0.f;
  for (int i = 0; i < 128; i++) {
    int l = c * 128 + i;
    sum += x[((size_t)b * L + l) * D + t];
  }
  atomicAdd(&relay[b * D + t], sum * (1.0f / L));
}

// ---------------- layernorm row kernel (D=128, 128 threads)
__global__ __launch_bounds__(128) void ln_kernel(
    const float* __restrict__ in, float* __restrict__ out,
    const float* __restrict__ g, const float* __restrict__ bb) {
  int row = blockIdx.x, t = threadIdx.x;
  float v = in[(size_t)row * D + t];
  float s = v, s2 = v * v;
#pragma unroll
  for (int o = 1; o < 64; o <<= 1) { s += __shfl_xor(s, o, 64); s2 += __shfl_xor(s2, o, 64); }
  __shared__ float rs[2], rs2[2];
  int w = t >> 6;
  if ((t & 63) == 0) { rs[w] = s; rs2[w] = s2; }
  __syncthreads();
  float S = rs[0] + rs[1], S2 = rs2[0] + rs2[1];
  float mu = S * (1.0f / D);
  float var = S2 * (1.0f / D) - mu * mu;
  float r = rsqrtf(var + EPS);
  out[(size_t)row * D + t] = (v - mu) * r * g[t] + bb[t];
}

// ---------------- generic GEMM: out[M,N] = A[M,K] @ W[N,K]^T + bias
__global__ __launch_bounds__(256) void gemm_kernel(
    const float* __restrict__ A, const float* __restrict__ W,
    const float* __restrict__ bias, float* __restrict__ out,
    const float* __restrict__ resid, int M, int N, int K,
    int relayrows, int residleaky) {
  __shared__ float As[64][36];
  __shared__ float Ws[64][36];
  int tid = threadIdx.x;
  int bm = blockIdx.x, bn = blockIdx.y;
  int tx = tid & 15, ty = tid >> 4;
  float acc[4][4] = {};
  const int rowA = bm * 64, rowW = bn * 64;
  for (int kt = 0; kt < K; kt += 32) {
#pragma unroll
    for (int i = 0; i < 8; i++) {
      int lin = tid + (i << 8);
      int r = lin >> 5, c = lin & 31;
      As[r][c] = A[(size_t)(rowA + r) * K + kt + c];
      Ws[r][c] = W[(size_t)(rowW + r) * K + kt + c];
    }
    __syncthreads();
#pragma unroll
    for (int kk = 0; kk < 32; kk += 4) {
      float4 av[4], bv[4];
#pragma unroll
      for (int i = 0; i < 4; i++) {
        av[i] = *(const float4*)&As[ty * 4 + i][kk];
        bv[i] = *(const float4*)&Ws[tx * 4 + i][kk];
      }
#pragma unroll
      for (int i = 0; i < 4; i++)
#pragma unroll
        for (int j = 0; j < 4; j++)
          acc[i][j] += av[i].x * bv[j].x + av[i].y * bv[j].y + av[i].z * bv[j].z + av[i].w * bv[j].w;
    }
    __syncthreads();
  }
#pragma unroll
  for (int i = 0; i < 4; i++) {
    int row = rowA + ty * 4 + i;
    int orow = relayrows ? (row + row / L + 1) : row;
#pragma unroll
    for (int j = 0; j < 4; j++) {
      int col = rowW + tx * 4 + j;
      float v = acc[i][j] + bias[col];
      if (residleaky) {
        v = (v > 0.f) ? v : 0.01f * v;
        v += resid[(size_t)row * N + col];
      }
      out[(size_t)orow * N + col] = v;
    }
  }
}

// ---------------- small matvec for relay-row projections
__global__ __launch_bounds__(128) void matvec_kernel(
    const float* __restrict__ A, const float* __restrict__ W, const float* __restrict__ bias,
    float* __restrict__ out, int K, int N, int outStride, int leaky) {
  __shared__ float as[512];
  int b = blockIdx.x;
  int n = blockIdx.y * 128 + threadIdx.x;
  for (int i = threadIdx.x; i < K; i += 128) as[i] = A[(size_t)b * K + i];
  __syncthreads();
  float acc = bias[n];
  const float2* w2 = (const float2*)(W + (size_t)n * K);
  for (int i = 0; i < K / 2; i++) { float2 wv = w2[i]; acc += as[2 * i] * wv.x + as[2 * i + 1] * wv.y; }
  if (leaky) acc = (acc > 0.f) ? acc : 0.01f * acc;
  out[(size_t)b * outStride + n] = acc;
}

// ---------------- ring (windowed) attention, 5 kv entries per (b,l,head)
__global__ __launch_bounds__(256) void ring_attn_kernel(
    const float* __restrict__ q, const float* __restrict__ k, const float* __restrict__ v,
    const float* __restrict__ akr, const float* __restrict__ avr,
    const float* __restrict__ rk, const float* __restrict__ rv,
    float* __restrict__ att) {
  int bl = blockIdx.x;
  int b = bl >> 11, l = bl & (L - 1);
  int n = threadIdx.x >> 6, lane = threadIdx.x & 63;
  int h = lane << 1;
  size_t base = (size_t)bl * D2 + n * HD + h;
  float q0 = q[base], q1 = q[base + 1];
  float s[5], v0[5], v1[5];
#pragma unroll
  for (int u = 0; u < 5; u++) {
    float k0 = 0.f, k1 = 0.f, vv0 = 0.f, vv1 = 0.f;
    if (u < 3) {
      int ll = l + u - 1;
      if (ll >= 0 && ll < L) {
        size_t off = ((size_t)b * L + ll) * D2 + n * HD + h;
        k0 = k[off]; k1 = k[off + 1]; vv0 = v[off]; vv1 = v[off + 1];
      }
    } else if (u == 3) {
      k0 = akr[base]; k1 = akr[base + 1]; vv0 = avr[base]; vv1 = avr[base + 1];
    } else {
      size_t rb = (size_t)b * D2 + n * HD + h;
      k0 = rk[rb]; k1 = rk[rb + 1]; vv0 = rv[rb]; vv1 = rv[rb + 1];
    }
    float p = q0 * k0 + q1 * k1;
#pragma unroll
    for (int o = 1; o < 64; o <<= 1) p += __shfl_xor(p, o, 64);
    s[u] = p * SCALE;
    v0[u] = vv0; v1[u] = vv1;
  }
  float m = s[0];
#pragma unroll
  for (int u = 1; u < 5; u++) m = fmaxf(m, s[u]);
  float sum = 0.f, o0 = 0.f, o1 = 0.f;
#pragma unroll
  for (int u = 0; u < 5; u++) {
    float e = expf(s[u] - m);
    sum += e; o0 += e * v0[u]; o1 += e * v1[u];
  }
  att[base] = o0 / sum;
  att[base + 1] = o1 / sum;
}

// ---------------- relay attention, phase 1: per-(b,head,chunk) partial softmax
__global__ __launch_bounds__(256) void relay_attn_partial(
    const float* __restrict__ sq, const float* __restrict__ sk, const float* __restrict__ sv,
    const int* __restrict__ mask,
    float* __restrict__ pm, float* __restrict__ ps, float* __restrict__ po) {
  int bn = blockIdx.x;           // b*NH + n
  int b = bn >> 2, n = bn & 3;
  int c = blockIdx.y;
  int l0 = c * CHUNK;
  int nloc = min(CHUNK, L1 - l0);  // always >= 1 (32*65=2080 >= 2049)
  __shared__ float sqs[HD];
  __shared__ float sc[CHUNK];
  __shared__ float red[4];
  __shared__ float accs[2][HD];
  int t = threadIdx.x;
  if (t < HD) sqs[t] = sq[(size_t)b * D2 + n * HD + t];
  __syncthreads();
  // scores: wave wv handles positions i = wv, wv+4, ...
  int wv = t >> 6, lane = t & 63;
  float2 qv = ((const float2*)sqs)[lane];
  for (int i = wv; i < nloc; i += 4) {
    int l = l0 + i;
    float2 kk = ((const float2*)(sk + ((size_t)b * L1 + l) * D2 + n * HD))[lane];
    float s = qv.x * kk.x + qv.y * kk.y;
#pragma unroll
    for (int o = 1; o < 64; o <<= 1) s += __shfl_xor(s, o, 64);
    if (lane == 0) {
      s *= SCALE;
      if (l > 0 && mask[b * L + l - 1] == 0) s = -1e30f;
      sc[i] = s;
    }
  }
  __syncthreads();
  // local max
  float m = -1e30f;
  for (int i = t; i < nloc; i += 256) m = fmaxf(m, sc[i]);
#pragma unroll
  for (int o = 1; o < 64; o <<= 1) m = fmaxf(m, __shfl_xor(m, o, 64));
  if (lane == 0) red[wv] = m;
  __syncthreads();
  m = fmaxf(fmaxf(red[0], red[1]), fmaxf(red[2], red[3]));
  __syncthreads();
  // exp + local sum
  float sum = 0.f;
  for (int i = t; i < nloc; i += 256) { float e = expf(sc[i] - m); sc[i] = e; sum += e; }
#pragma unroll
  for (int o = 1; o < 64; o <<= 1) sum += __shfl_xor(sum, o, 64);
  if (lane == 0) red[wv] = sum;
  __syncthreads();
  sum = red[0] + red[1] + red[2] + red[3];
  // partial weighted V: 256 threads = 2 parities x 128 dims
  int h = t & 127, p = t >> 7;
  float o = 0.f;
  for (int i = p; i < nloc; i += 2)
    o += sc[i] * sv[((size_t)b * L1 + l0 + i) * D2 + n * HD + h];
  accs[p][h] = o;
  __syncthreads();
  if (t < HD) po[((size_t)bn * NCH + c) * HD + t] = accs[0][t] + accs[1][t];
  if (t == 0) { pm[bn * NCH + c] = m; ps[bn * NCH + c] = sum; }
}

// ---------------- relay attention, phase 2: combine chunk partials
__global__ __launch_bounds__(128) void relay_attn_combine(
    const float* __restrict__ pm, const float* __restrict__ ps, const float* __restrict__ po,
    float* __restrict__ satt) {
  int bn = blockIdx.x;
  int b = bn >> 2, n = bn & 3;
  int t = threadIdx.x;
  float M = -1e30f;
#pragma unroll
  for (int c = 0; c < NCH; c++) M = fmaxf(M, pm[bn * NCH + c]);
  float S = 0.f, O = 0.f;
#pragma unroll
  for (int c = 0; c < NCH; c++) {
    float w = expf(pm[bn * NCH + c] - M);
    S += ps[bn * NCH + c] * w;
    O += po[((size_t)bn * NCH + c) * HD + t] * w;
  }
  satt[(size_t)b * D2 + n * HD + t] = O / S;
}

// ---------------- zero nodes at padded positions
__global__ __launch_bounds__(256) void mask_nodes_kernel(float* __restrict__ nodes, const int* __restrict__ mask) {
  int idx = blockIdx.x * 256 + threadIdx.x;
  int bl = idx >> 7;
  if (mask[bl] == 0) nodes[idx] = 0.f;
}

extern "C" void kernel_launch(void* const* d_in, const int* in_sizes, int n_in,
                              void* d_out, int out_size, void* d_ws, size_t ws_size,
                              hipStream_t stream) {
  const int* tokens = (const int*)d_in[0];
  const int* mask = (const int*)d_in[1];
  const float* emb = (const float*)d_in[2];
  const float* proj_w = (const float*)d_in[3];
  const float* proj_b = (const float*)d_in[4];
  const float* ng = (const float*)d_in[5];
  const float* nb = (const float*)d_in[6];
  const float* rq_w = (const float*)d_in[7], * rq_b = (const float*)d_in[8];
  const float* rk_w = (const float*)d_in[9], * rk_b = (const float*)d_in[10];
  const float* rv_w = (const float*)d_in[11], * rv_b = (const float*)d_in[12];
  const float* ro_w = (const float*)d_in[13], * ro_b = (const float*)d_in[14];
  const float* sq_w = (const float*)d_in[15], * sq_b = (const float*)d_in[16];
  const float* sk_w = (const float*)d_in[17], * sk_b = (const float*)d_in[18];
  const float* sv_w = (const float*)d_in[19], * sv_b = (const float*)d_in[20];
  const float* so_w = (const float*)d_in[21], * so_b = (const float*)d_in[22];

  float* ws = (float*)d_ws;
  const size_t BLD = (size_t)B * L * D;       // 1,048,576
  const size_t SLOT = (size_t)B * L1 * D2;    // 4,196,352
  float* x = ws;
  float* nodes = x + BLD;
  float* nx = nodes + BLD;
  float* relay = nx + BLD;
  float* relay_k = relay + B * D;
  float* relay_v = relay_k + B * D2;
  float* sqv = relay_v + B * D2;
  float* satt = sqv + B * D2;
  float* slot0 = satt + B * D2;   // q, later sk
  float* slot1 = slot0 + SLOT;    // k, later sv
  float* slot2 = slot1 + SLOT;    // v
  float* slot3 = slot2 + SLOT;    // ak (r_embs)
  float* slot4 = slot3 + SLOT;    // av (r_embs)
  float* slot5 = slot4 + SLOT;    // att
  float* pm = slot5 + SLOT;       // [B*NH, NCH]
  float* ps = pm + B * NH * NCH;
  float* po = ps + B * NH * NCH;  // [B*NH, NCH, HD]
  // total ~113.6 MB of fp32 scratch

  hipMemsetAsync(relay, 0, B * D * sizeof(float), stream);
  embed_proj_kernel<<<B * L, 128, 0, stream>>>(tokens, emb, proj_w, proj_b, x, nodes);
  relay_init_kernel<<<B * 16, 128, 0, stream>>>(x, relay);

  const dim3 g8(128, 8), g2(128, 2);
  for (int i = 0; i < NL; i++) {
    const float* rqwi = rq_w + (size_t)i * D2 * D, * rqbi = rq_b + (size_t)i * D2;
    const float* rkwi = rk_w + (size_t)i * D2 * D, * rkbi = rk_b + (size_t)i * D2;
    const float* rvwi = rv_w + (size_t)i * D2 * D, * rvbi = rv_b + (size_t)i * D2;
    const float* rowi = ro_w + (size_t)i * D * D2, * robi = ro_b + (size_t)i * D;
    const float* sqwi = sq_w + (size_t)i * D2 * D, * sqbi = sq_b + (size_t)i * D2;
    const float* skwi = sk_w + (size_t)i * D2 * D, * skbi = sk_b + (size_t)i * D2;
    const float* svwi = sv_w + (size_t)i * D2 * D, * svbi = sv_b + (size_t)i * D2;
    const float* sowi = so_w + (size_t)i * D * D2, * sobi = so_b + (size_t)i * D;

    ln_kernel<<<B * L, 128, 0, stream>>>(nodes, nx, ng + i * D, nb + i * D);
    // q, k, v from nx; ak, av from original embeddings x
    gemm_kernel<<<g8, 256, 0, stream>>>(nx, rqwi, rqbi, slot0, nullptr, B * L, D2, D, 0, 0);
    gemm_kernel<<<g8, 256, 0, stream>>>(nx, rkwi, rkbi, slot1, nullptr, B * L, D2, D, 0, 0);
    gemm_kernel<<<g8, 256, 0, stream>>>(nx, rvwi, rvbi, slot2, nullptr, B * L, D2, D, 0, 0);
    gemm_kernel<<<g8, 256, 0, stream>>>(x, rkwi, rkbi, slot3, nullptr, B * L, D2, D, 0, 0);
    gemm_kernel<<<g8, 256, 0, stream>>>(x, rvwi, rvbi, slot4, nullptr, B * L, D2, D, 0, 0);
    // relay entries of ring attention (from layer-entry relay)
    matvec_kernel<<<dim3(B, 4), 128, 0, stream>>>(relay, rkwi, rkbi, relay_k, D, D2, D2, 0);
    matvec_kernel<<<dim3(B, 4), 128, 0, stream>>>(relay, rvwi, rvbi, relay_v, D, D2, D2, 0);
    ring_attn_kernel<<<B * L, 256, 0, stream>>>(slot0, slot1, slot2, slot3, slot4, relay_k, relay_v, slot5);
    // nodes += leaky_relu(att @ ro_w.T + ro_b)
    gemm_kernel<<<g2, 256, 0, stream>>>(slot5, rowi, robi, nodes, nodes, B * L, D, D2, 0, 1);
    // MSA2
    matvec_kernel<<<dim3(B, 4), 128, 0, stream>>>(relay, sqwi, sqbi, sqv, D, D2, D2, 0);
    gemm_kernel<<<g8, 256, 0, stream>>>(nodes, skwi, skbi, slot0, nullptr, B * L, D2, D, 1, 0);
    matvec_kernel<<<dim3(B, 4), 128, 0, stream>>>(relay, skwi, skbi, slot0, D, D2, L1 * D2, 0);
    gemm_kernel<<<g8, 256, 0, stream>>>(nodes, svwi, svbi, slot1, nullptr, B * L, D2, D, 1, 0);
    matvec_kernel<<<dim3(B, 4), 128, 0, stream>>>(relay, svwi, svbi, slot1, D, D2, L1 * D2, 0);
    relay_attn_partial<<<dim3(B * NH, NCH), 256, 0, stream>>>(sqv, slot0, slot1, mask, pm, ps, po);
    relay_attn_combine<<<B * NH, 128, 0, stream>>>(pm, ps, po, satt);
    // relay = leaky_relu(satt @ so_w.T + so_b); last layer writes d_out directly
    float* relay_dst = (i == NL - 1) ? (float*)d_out : relay;
    matvec_kernel<<<dim3(B, 1), 128, 0, stream>>>(satt, sowi, sobi, relay_dst, D2, D, D, 1);
    // nodes = where(pad, 0, nodes)
    mask_nodes_kernel<<<(B * L * D) / 256, 256, 0, stream>>>(nodes, mask);
  }
}

// Round 4
// 771.388 us; speedup vs baseline: 2.4418x; 1.6463x over previous
//
#include <hip/hip_runtime.h>
#include <hip/hip_bf16.h>

// Problem constants
constexpr int B = 4, L = 2048, E = 300, D = 128, NH = 4, HD = 128, NL = 3, D2 = 512;
constexpr int L1 = L + 1; // 2049
constexpr float EPS = 1e-5f;
constexpr float SCALE = 0.08838834764831843f; // 1/sqrt(128)
constexpr int NCH = 32;              // relay-attention L-chunks
constexpr int CHUNK = 65;            // ceil(2049/32)

typedef unsigned int uint_t;
typedef short bf16x8 __attribute__((ext_vector_type(8)));
typedef float f32x4 __attribute__((ext_vector_type(4)));

__device__ __forceinline__ unsigned short f2bf(float f) {
  union { float f; uint_t i; } x; x.f = f;
  uint_t r = x.i + 0x7fffu + ((x.i >> 16) & 1u);
  return (unsigned short)(r >> 16);
}
__device__ __forceinline__ uint_t packbf(float a, float b) {
  return (uint_t)f2bf(a) | ((uint_t)f2bf(b) << 16);
}

// ================= generic bf16-MFMA GEMM: out[M,N] = A[M,K] @ W[N,K]^T + bias
// 128x128 block tile, BK=64 LDS staging, 4 waves each computing 64x64.
// Descriptor batching: blockIdx.y / nb selects the descriptor.
struct GDesc {
  const float* A; const float* W; const float* bias;
  float* out; const float* resid; float* out2;
  const int* gather;       // if set: A row r -> A + gather[r]*K
  int relayrows, residleaky;
};
struct GArgs { GDesc d[5]; };

__global__ __launch_bounds__(256) void gemm_mfma(
    GArgs ga, int nb, int N, int K) {
  __shared__ unsigned short As[128][72];  // +8 pad: 16B-aligned rows, even bank spread
  __shared__ unsigned short Ws[128][72];
  int t = threadIdx.x;
  int bm = blockIdx.x;
  int di = blockIdx.y / nb, bn = blockIdx.y - di * nb;
  GDesc d = ga.d[di];
  const int rowA = bm * 128, rowW = bn * 128;

  f32x4 acc[4][4];
#pragma unroll
  for (int i = 0; i < 4; i++)
#pragma unroll
    for (int j = 0; j < 4; j++)
      acc[i][j] = (f32x4){0.f, 0.f, 0.f, 0.f};

  const int srow = t >> 4;            // 0..15
  const int sc4 = (t & 15) * 4;       // col within BK
  const int wm = ((t >> 7) & 1) * 64; // wave m-quadrant
  const int wn = ((t >> 6) & 1) * 64; // wave n-quadrant
  const int lr = t & 15, quad = (t >> 4) & 3;

  for (int kt = 0; kt < K; kt += 64) {
    __syncthreads();
    bool full = (kt + 64 <= K);
#pragma unroll
    for (int i = 0; i < 8; i++) {
      int r = srow + i * 16;
      const float* Arow = d.gather ? d.A + (size_t)d.gather[rowA + r] * K
                                   : d.A + (size_t)(rowA + r) * K;
      const float* Wrow = d.W + (size_t)(rowW + r) * K;
      float4 fa, fw;
      if (full) {
        fa = *(const float4*)(Arow + kt + sc4);
        fw = *(const float4*)(Wrow + kt + sc4);
      } else {
        int c = kt + sc4;
        fa.x = (c + 0 < K) ? Arow[c + 0] : 0.f;
        fa.y = (c + 1 < K) ? Arow[c + 1] : 0.f;
        fa.z = (c + 2 < K) ? Arow[c + 2] : 0.f;
        fa.w = (c + 3 < K) ? Arow[c + 3] : 0.f;
        fw.x = (c + 0 < K) ? Wrow[c + 0] : 0.f;
        fw.y = (c + 1 < K) ? Wrow[c + 1] : 0.f;
        fw.z = (c + 2 < K) ? Wrow[c + 2] : 0.f;
        fw.w = (c + 3 < K) ? Wrow[c + 3] : 0.f;
      }
      *(uint2*)&As[r][sc4] = make_uint2(packbf(fa.x, fa.y), packbf(fa.z, fa.w));
      *(uint2*)&Ws[r][sc4] = make_uint2(packbf(fw.x, fw.y), packbf(fw.z, fw.w));
    }
    __syncthreads();
#pragma unroll
    for (int ks = 0; ks < 2; ks++) {
      bf16x8 af[4], bfr[4];
#pragma unroll
      for (int mt = 0; mt < 4; mt++)
        af[mt] = *(const bf16x8*)&As[wm + mt * 16 + lr][ks * 32 + quad * 8];
#pragma unroll
      for (int nt = 0; nt < 4; nt++)
        bfr[nt] = *(const bf16x8*)&Ws[wn + nt * 16 + lr][ks * 32 + quad * 8];
#pragma unroll
      for (int mt = 0; mt < 4; mt++)
#pragma unroll
        for (int nt = 0; nt < 4; nt++)
          acc[mt][nt] = __builtin_amdgcn_mfma_f32_16x16x32_bf16(af[mt], bfr[nt], acc[mt][nt], 0, 0, 0);
    }
  }

  // epilogue: C/D layout col=lane&15, row=quad*4+reg
#pragma unroll
  for (int nt = 0; nt < 4; nt++) {
    int col = rowW + wn + nt * 16 + lr;
    float bv = d.bias[col];
#pragma unroll
    for (int mt = 0; mt < 4; mt++) {
#pragma unroll
      for (int r = 0; r < 4; r++) {
        int row = rowA + wm + mt * 16 + quad * 4 + r;
        float v = acc[mt][nt][r] + bv;
        if (d.residleaky) {
          v = (v > 0.f) ? v : 0.01f * v;
          v += d.resid[(size_t)row * N + col];
        }
        int orow = d.relayrows ? row + (row >> 11) + 1 : row;  // row/L + 1, L=2048
        d.out[(size_t)orow * N + col] = v;
        if (d.out2) d.out2[(size_t)orow * N + col] = v;
      }
    }
  }
}

// ---------------- relay = mean over L of x  (relay must be zeroed first)
__global__ __launch_bounds__(128) void relay_init_kernel(const float* __restrict__ x, float* __restrict__ relay) {
  int b = blockIdx.x >> 4, c = blockIdx.x & 15, t = threadIdx.x;
  float sum = 0.f;
  for (int i = 0; i < 128; i++) {
    int l = c * 128 + i;
    sum += x[((size_t)b * L + l) * D + t];
  }
  atomicAdd(&relay[b * D + t], sum * (1.0f / L));
}

// ---------------- layernorm row kernel (D=128, 128 threads)
__global__ __launch_bounds__(128) void ln_kernel(
    const float* __restrict__ in, float* __restrict__ out,
    const float* __restrict__ g, const float* __restrict__ bb) {
  int row = blockIdx.x, t = threadIdx.x;
  float v = in[(size_t)row * D + t];
  float s = v, s2 = v * v;
#pragma unroll
  for (int o = 1; o < 64; o <<= 1) { s += __shfl_xor(s, o, 64); s2 += __shfl_xor(s2, o, 64); }
  __shared__ float rs[2], rs2[2];
  int w = t >> 6;
  if ((t & 63) == 0) { rs[w] = s; rs2[w] = s2; }
  __syncthreads();
  float S = rs[0] + rs[1], S2 = rs2[0] + rs2[1];
  float mu = S * (1.0f / D);
  float var = S2 * (1.0f / D) - mu * mu;
  float r = rsqrtf(var + EPS);
  out[(size_t)row * D + t] = (v - mu) * r * g[t] + bb[t];
}

// ---------------- small matvec for relay-row projections
__global__ __launch_bounds__(128) void matvec_kernel(
    const float* __restrict__ A, const float* __restrict__ W, const float* __restrict__ bias,
    float* __restrict__ out, int K, int N, int outStride, int leaky) {
  __shared__ float as[512];
  int b = blockIdx.x;
  int n = blockIdx.y * 128 + threadIdx.x;
  for (int i = threadIdx.x; i < K; i += 128) as[i] = A[(size_t)b * K + i];
  __syncthreads();
  float acc = bias[n];
  const float2* w2 = (const float2*)(W + (size_t)n * K);
  for (int i = 0; i < K / 2; i++) { float2 wv = w2[i]; acc += as[2 * i] * wv.x + as[2 * i + 1] * wv.y; }
  if (leaky) acc = (acc > 0.f) ? acc : 0.01f * acc;
  out[(size_t)b * outStride + n] = acc;
}

// ---------------- ring (windowed) attention, 5 kv entries per (b,l,head)
__global__ __launch_bounds__(256) void ring_attn_kernel(
    const float* __restrict__ q, const float* __restrict__ k, const float* __restrict__ v,
    const float* __restrict__ akr, const float* __restrict__ avr,
    const float* __restrict__ rk, const float* __restrict__ rv,
    float* __restrict__ att) {
  int bl = blockIdx.x;
  int b = bl >> 11, l = bl & (L - 1);
  int n = threadIdx.x >> 6, lane = threadIdx.x & 63;
  int h = lane << 1;
  size_t base = (size_t)bl * D2 + n * HD + h;
  float q0 = q[base], q1 = q[base + 1];
  float s[5], v0[5], v1[5];
#pragma unroll
  for (int u = 0; u < 5; u++) {
    float k0 = 0.f, k1 = 0.f, vv0 = 0.f, vv1 = 0.f;
    if (u < 3) {
      int ll = l + u - 1;
      if (ll >= 0 && ll < L) {
        size_t off = ((size_t)b * L + ll) * D2 + n * HD + h;
        k0 = k[off]; k1 = k[off + 1]; vv0 = v[off]; vv1 = v[off + 1];
      }
    } else if (u == 3) {
      k0 = akr[base]; k1 = akr[base + 1]; vv0 = avr[base]; vv1 = avr[base + 1];
    } else {
      size_t rb = (size_t)b * D2 + n * HD + h;
      k0 = rk[rb]; k1 = rk[rb + 1]; vv0 = rv[rb]; vv1 = rv[rb + 1];
    }
    float p = q0 * k0 + q1 * k1;
#pragma unroll
    for (int o = 1; o < 64; o <<= 1) p += __shfl_xor(p, o, 64);
    s[u] = p * SCALE;
    v0[u] = vv0; v1[u] = vv1;
  }
  float m = s[0];
#pragma unroll
  for (int u = 1; u < 5; u++) m = fmaxf(m, s[u]);
  float sum = 0.f, o0 = 0.f, o1 = 0.f;
#pragma unroll
  for (int u = 0; u < 5; u++) {
    float e = expf(s[u] - m);
    sum += e; o0 += e * v0[u]; o1 += e * v1[u];
  }
  att[base] = o0 / sum;
  att[base + 1] = o1 / sum;
}

// ---------------- relay attention, phase 1: per-(b,head,chunk) partial softmax
__global__ __launch_bounds__(256) void relay_attn_partial(
    const float* __restrict__ sq, const float* __restrict__ sk, const float* __restrict__ sv,
    const int* __restrict__ mask,
    float* __restrict__ pm, float* __restrict__ ps, float* __restrict__ po) {
  int bn = blockIdx.x;           // b*NH + n
  int b = bn >> 2, n = bn & 3;
  int c = blockIdx.y;
  int l0 = c * CHUNK;
  int nloc = min(CHUNK, L1 - l0);
  __shared__ float sqs[HD];
  __shared__ float sc[CHUNK];
  __shared__ float red[4];
  __shared__ float accs[2][HD];
  int t = threadIdx.x;
  if (t < HD) sqs[t] = sq[(size_t)b * D2 + n * HD + t];
  __syncthreads();
  int wv = t >> 6, lane = t & 63;
  float2 qv = ((const float2*)sqs)[lane];
  for (int i = wv; i < nloc; i += 4) {
    int l = l0 + i;
    float2 kk = ((const float2*)(sk + ((size_t)b * L1 + l) * D2 + n * HD))[lane];
    float s = qv.x * kk.x + qv.y * kk.y;
#pragma unroll
    for (int o = 1; o < 64; o <<= 1) s += __shfl_xor(s, o, 64);
    if (lane == 0) {
      s *= SCALE;
      if (l > 0 && mask[b * L + l - 1] == 0) s = -1e30f;
      sc[i] = s;
    }
  }
  __syncthreads();
  float m = -1e30f;
  for (int i = t; i < nloc; i += 256) m = fmaxf(m, sc[i]);
#pragma unroll
  for (int o = 1; o < 64; o <<= 1) m = fmaxf(m, __shfl_xor(m, o, 64));
  if (lane == 0) red[wv] = m;
  __syncthreads();
  m = fmaxf(fmaxf(red[0], red[1]), fmaxf(red[2], red[3]));
  __syncthreads();
  float sum = 0.f;
  for (int i = t; i < nloc; i += 256) { float e = expf(sc[i] - m); sc[i] = e; sum += e; }
#pragma unroll
  for (int o = 1; o < 64; o <<= 1) sum += __shfl_xor(sum, o, 64);
  if (lane == 0) red[wv] = sum;
  __syncthreads();
  sum = red[0] + red[1] + red[2] + red[3];
  int h = t & 127, p = t >> 7;
  float o = 0.f;
  for (int i = p; i < nloc; i += 2)
    o += sc[i] * sv[((size_t)b * L1 + l0 + i) * D2 + n * HD + h];
  accs[p][h] = o;
  __syncthreads();
  if (t < HD) po[((size_t)bn * NCH + c) * HD + t] = accs[0][t] + accs[1][t];
  if (t == 0) { pm[bn * NCH + c] = m; ps[bn * NCH + c] = sum; }
}

// ---------------- relay attention, phase 2: combine chunk partials
__global__ __launch_bounds__(128) void relay_attn_combine(
    const float* __restrict__ pm, const float* __restrict__ ps, const float* __restrict__ po,
    float* __restrict__ satt) {
  int bn = blockIdx.x;
  int b = bn >> 2, n = bn & 3;
  int t = threadIdx.x;
  float M = -1e30f;
#pragma unroll
  for (int c = 0; c < NCH; c++) M = fmaxf(M, pm[bn * NCH + c]);
  float S = 0.f, O = 0.f;
#pragma unroll
  for (int c = 0; c < NCH; c++) {
    float w = expf(pm[bn * NCH + c] - M);
    S += ps[bn * NCH + c] * w;
    O += po[((size_t)bn * NCH + c) * HD + t] * w;
  }
  satt[(size_t)b * D2 + n * HD + t] = O / S;
}

// ---------------- zero nodes at padded positions
__global__ __launch_bounds__(256) void mask_nodes_kernel(float* __restrict__ nodes, const int* __restrict__ mask) {
  int idx = blockIdx.x * 256 + threadIdx.x;
  int bl = idx >> 7;
  if (mask[bl] == 0) nodes[idx] = 0.f;
}

extern "C" void kernel_launch(void* const* d_in, const int* in_sizes, int n_in,
                              void* d_out, int out_size, void* d_ws, size_t ws_size,
                              hipStream_t stream) {
  const int* tokens = (const int*)d_in[0];
  const int* mask = (const int*)d_in[1];
  const float* emb = (const float*)d_in[2];
  const float* proj_w = (const float*)d_in[3];
  const float* proj_b = (const float*)d_in[4];
  const float* ng = (const float*)d_in[5];
  const float* nb = (const float*)d_in[6];
  const float* rq_w = (const float*)d_in[7], * rq_b = (const float*)d_in[8];
  const float* rk_w = (const float*)d_in[9], * rk_b = (const float*)d_in[10];
  const float* rv_w = (const float*)d_in[11], * rv_b = (const float*)d_in[12];
  const float* ro_w = (const float*)d_in[13], * ro_b = (const float*)d_in[14];
  const float* sq_w = (const float*)d_in[15], * sq_b = (const float*)d_in[16];
  const float* sk_w = (const float*)d_in[17], * sk_b = (const float*)d_in[18];
  const float* sv_w = (const float*)d_in[19], * sv_b = (const float*)d_in[20];
  const float* so_w = (const float*)d_in[21], * so_b = (const float*)d_in[22];

  float* ws = (float*)d_ws;
  const size_t BLD = (size_t)B * L * D;       // 1,048,576
  const size_t SLOT = (size_t)B * L1 * D2;    // 4,196,352
  float* x = ws;
  float* nodes = x + BLD;
  float* nx = nodes + BLD;
  float* relay = nx + BLD;
  float* relay_k = relay + B * D;
  float* relay_v = relay_k + B * D2;
  float* sqv = relay_v + B * D2;
  float* satt = sqv + B * D2;
  float* slot0 = satt + B * D2;   // q, later sk
  float* slot1 = slot0 + SLOT;    // k, later sv
  float* slot2 = slot1 + SLOT;    // v
  float* slot3 = slot2 + SLOT;    // ak (r_embs)
  float* slot4 = slot3 + SLOT;    // av (r_embs)
  float* slot5 = slot4 + SLOT;    // att
  float* pm = slot5 + SLOT;       // [B*NH, NCH]
  float* ps = pm + B * NH * NCH;
  float* po = ps + B * NH * NCH;  // [B*NH, NCH, HD]

  hipMemsetAsync(relay, 0, B * D * sizeof(float), stream);

  // embedding projection as gathered-A MFMA GEMM: [8192,300] @ [128,300]^T
  {
    GArgs ga = {};
    ga.d[0] = {emb, proj_w, proj_b, x, nullptr, nodes, tokens, 0, 0};
    gemm_mfma<<<dim3(64, 1), 256, 0, stream>>>(ga, 1, D, E);
  }
  relay_init_kernel<<<B * 16, 128, 0, stream>>>(x, relay);

  for (int i = 0; i < NL; i++) {
    const float* rqwi = rq_w + (size_t)i * D2 * D, * rqbi = rq_b + (size_t)i * D2;
    const float* rkwi = rk_w + (size_t)i * D2 * D, * rkbi = rk_b + (size_t)i * D2;
    const float* rvwi = rv_w + (size_t)i * D2 * D, * rvbi = rv_b + (size_t)i * D2;
    const float* rowi = ro_w + (size_t)i * D * D2, * robi = ro_b + (size_t)i * D;
    const float* sqwi = sq_w + (size_t)i * D2 * D, * sqbi = sq_b + (size_t)i * D2;
    const float* skwi = sk_w + (size_t)i * D2 * D, * skbi = sk_b + (size_t)i * D2;
    const float* svwi = sv_w + (size_t)i * D2 * D, * svbi = sv_b + (size_t)i * D2;
    const float* sowi = so_w + (size_t)i * D * D2, * sobi = so_b + (size_t)i * D;

    ln_kernel<<<B * L, 128, 0, stream>>>(nodes, nx, ng + i * D, nb + i * D);

    // fused q,k,v (from nx) + ak,av (from x): one dispatch, 1280 blocks
    {
      GArgs ga = {};
      ga.d[0] = {nx, rqwi, rqbi, slot0, nullptr, nullptr, nullptr, 0, 0};
      ga.d[1] = {nx, rkwi, rkbi, slot1, nullptr, nullptr, nullptr, 0, 0};
      ga.d[2] = {nx, rvwi, rvbi, slot2, nullptr, nullptr, nullptr, 0, 0};
      ga.d[3] = {x,  rkwi, rkbi, slot3, nullptr, nullptr, nullptr, 0, 0};
      ga.d[4] = {x,  rvwi, rvbi, slot4, nullptr, nullptr, nullptr, 0, 0};
      gemm_mfma<<<dim3(64, 20), 256, 0, stream>>>(ga, 4, D2, D);
    }
    // relay entries of ring attention (from layer-entry relay)
    matvec_kernel<<<dim3(B, 4), 128, 0, stream>>>(relay, rkwi, rkbi, relay_k, D, D2, D2, 0);
    matvec_kernel<<<dim3(B, 4), 128, 0, stream>>>(relay, rvwi, rvbi, relay_v, D, D2, D2, 0);
    ring_attn_kernel<<<B * L, 256, 0, stream>>>(slot0, slot1, slot2, slot3, slot4, relay_k, relay_v, slot5);
    // nodes += leaky_relu(att @ ro_w.T + ro_b)
    {
      GArgs ga = {};
      ga.d[0] = {slot5, rowi, robi, nodes, nodes, nullptr, nullptr, 0, 1};
      gemm_mfma<<<dim3(64, 1), 256, 0, stream>>>(ga, 1, D, D2);
    }
    // MSA2
    matvec_kernel<<<dim3(B, 4), 128, 0, stream>>>(relay, sqwi, sqbi, sqv, D, D2, D2, 0);
    {
      GArgs ga = {};
      ga.d[0] = {nodes, skwi, skbi, slot0, nullptr, nullptr, nullptr, 1, 0};
      ga.d[1] = {nodes, svwi, svbi, slot1, nullptr, nullptr, nullptr, 1, 0};
      gemm_mfma<<<dim3(64, 8), 256, 0, stream>>>(ga, 4, D2, D);
    }
    matvec_kernel<<<dim3(B, 4), 128, 0, stream>>>(relay, skwi, skbi, slot0, D, D2, L1 * D2, 0);
    matvec_kernel<<<dim3(B, 4), 128, 0, stream>>>(relay, svwi, svbi, slot1, D, D2, L1 * D2, 0);
    relay_attn_partial<<<dim3(B * NH, NCH), 256, 0, stream>>>(sqv, slot0, slot1, mask, pm, ps, po);
    relay_attn_combine<<<B * NH, 128, 0, stream>>>(pm, ps, po, satt);
    // relay = leaky_relu(satt @ so_w.T + so_b); last layer writes d_out directly
    float* relay_dst = (i == NL - 1) ? (float*)d_out : relay;
    matvec_kernel<<<dim3(B, 1), 128, 0, stream>>>(satt, sowi, sobi, relay_dst, D2, D, D, 1);
    // nodes = where(pad, 0, nodes)
    mask_nodes_kernel<<<(B * L * D) / 256, 256, 0, stream>>>(nodes, mask);
  }
}

// Round 5
// 651.551 us; speedup vs baseline: 2.8909x; 1.1839x over previous
//
#include <hip/hip_runtime.h>
#include <hip/hip_bf16.h>

// Problem constants
constexpr int B = 4, L = 2048, E = 300, D = 128, NH = 4, HD = 128, NL = 3, D2 = 512;
constexpr int L1 = L + 1; // 2049
constexpr float EPS = 1e-5f;
constexpr float SCALE = 0.08838834764831843f; // 1/sqrt(128)
constexpr int NCH = 32;              // relay-attention L-chunks
constexpr int CHUNK = 65;            // ceil(2049/32)

typedef unsigned int uint_t;
typedef short bf16x8 __attribute__((ext_vector_type(8)));
typedef float f32x4 __attribute__((ext_vector_type(4)));

__device__ __forceinline__ unsigned short f2bf(float f) {
  union { float f; uint_t i; } x; x.f = f;
  uint_t r = x.i + 0x7fffu + ((x.i >> 16) & 1u);
  return (unsigned short)(r >> 16);
}
__device__ __forceinline__ uint_t packbf(float a, float b) {
  return (uint_t)f2bf(a) | ((uint_t)f2bf(b) << 16);
}

// ================= bf16-MFMA GEMM: out[M,N] = A[M,K] @ W[N,K]^T + bias
// 64x64 block tile, BK=64, 256 threads = 4 waves as 2x2, each wave 32x32.
struct GDesc {
  const float* A; const float* W; const float* bias;
  float* out; const float* resid; float* out2;
  const int* gather;       // if set: A row r -> A + gather[r]*K
  const int* mask;         // if set (with residleaky): zero padded rows
  int relayrows, residleaky;
};
struct GArgs { GDesc d[5]; };

__global__ __launch_bounds__(256) void gemm_mfma(
    GArgs ga, int nby, int N, int K) {
  __shared__ unsigned short As[64][72];
  __shared__ unsigned short Ws[64][72];
  int t = threadIdx.x;
  int bm = blockIdx.x;
  int di = blockIdx.y / nby, bn = blockIdx.y - di * nby;
  GDesc d = ga.d[di];
  const int rowA = bm * 64, rowW = bn * 64;

  f32x4 acc[2][2];
#pragma unroll
  for (int i = 0; i < 2; i++)
#pragma unroll
    for (int j = 0; j < 2; j++)
      acc[i][j] = (f32x4){0.f, 0.f, 0.f, 0.f};

  const int srow = t >> 2;            // 0..63
  const int sc0 = (t & 3) * 16;       // 0,16,32,48
  const int wid = t >> 6;
  const int wm = (wid & 1) * 32, wn = (wid >> 1) * 32;
  const int lr = t & 15, quad = (t >> 4) & 3;

  const float* Arow = d.gather ? d.A + (size_t)d.gather[rowA + srow] * K
                               : d.A + (size_t)(rowA + srow) * K;
  const float* Wrow = d.W + (size_t)(rowW + srow) * K;

  for (int kt = 0; kt < K; kt += 64) {
    __syncthreads();
    bool full = (kt + 64 <= K);
#pragma unroll
    for (int ch = 0; ch < 4; ch++) {
      int c = kt + sc0 + ch * 4;
      float4 fa, fw;
      if (full) {
        fa = *(const float4*)(Arow + c);
        fw = *(const float4*)(Wrow + c);
      } else {
        fa.x = (c + 0 < K) ? Arow[c + 0] : 0.f;
        fa.y = (c + 1 < K) ? Arow[c + 1] : 0.f;
        fa.z = (c + 2 < K) ? Arow[c + 2] : 0.f;
        fa.w = (c + 3 < K) ? Arow[c + 3] : 0.f;
        fw.x = (c + 0 < K) ? Wrow[c + 0] : 0.f;
        fw.y = (c + 1 < K) ? Wrow[c + 1] : 0.f;
        fw.z = (c + 2 < K) ? Wrow[c + 2] : 0.f;
        fw.w = (c + 3 < K) ? Wrow[c + 3] : 0.f;
      }
      *(uint2*)&As[srow][sc0 + ch * 4] = make_uint2(packbf(fa.x, fa.y), packbf(fa.z, fa.w));
      *(uint2*)&Ws[srow][sc0 + ch * 4] = make_uint2(packbf(fw.x, fw.y), packbf(fw.z, fw.w));
    }
    __syncthreads();
#pragma unroll
    for (int ks = 0; ks < 2; ks++) {
      bf16x8 af[2], bfr[2];
#pragma unroll
      for (int mt = 0; mt < 2; mt++)
        af[mt] = *(const bf16x8*)&As[wm + mt * 16 + lr][ks * 32 + quad * 8];
#pragma unroll
      for (int nt = 0; nt < 2; nt++)
        bfr[nt] = *(const bf16x8*)&Ws[wn + nt * 16 + lr][ks * 32 + quad * 8];
#pragma unroll
      for (int mt = 0; mt < 2; mt++)
#pragma unroll
        for (int nt = 0; nt < 2; nt++)
          acc[mt][nt] = __builtin_amdgcn_mfma_f32_16x16x32_bf16(af[mt], bfr[nt], acc[mt][nt], 0, 0, 0);
    }
  }

  // epilogue: C/D layout col=lane&15, row=quad*4+reg
#pragma unroll
  for (int nt = 0; nt < 2; nt++) {
    int col = rowW + wn + nt * 16 + lr;
    float bv = d.bias[col];
#pragma unroll
    for (int mt = 0; mt < 2; mt++) {
#pragma unroll
      for (int r = 0; r < 4; r++) {
        int row = rowA + wm + mt * 16 + quad * 4 + r;
        float v = acc[mt][nt][r] + bv;
        if (d.residleaky) {
          v = (v > 0.f) ? v : 0.01f * v;
          v += d.resid[(size_t)row * N + col];
          if (d.mask && d.mask[row] == 0) v = 0.f;
        }
        int orow = d.relayrows ? row + (row >> 11) + 1 : row;  // row/L + 1, L=2048
        d.out[(size_t)orow * N + col] = v;
        if (d.out2) d.out2[(size_t)orow * N + col] = v;
      }
    }
  }
}

// ---------------- relay = mean over L of x  (relay must be zeroed first)
__global__ __launch_bounds__(128) void relay_init_kernel(const float* __restrict__ x, float* __restrict__ relay) {
  int b = blockIdx.x >> 6, c = blockIdx.x & 63, t = threadIdx.x;
  float sum = 0.f;
  for (int i = 0; i < 32; i++) {
    int l = c * 32 + i;
    sum += x[((size_t)b * L + l) * D + t];
  }
  atomicAdd(&relay[b * D + t], sum * (1.0f / L));
}

// ---------------- layernorm row kernel (D=128, 128 threads)
__global__ __launch_bounds__(128) void ln_kernel(
    const float* __restrict__ in, float* __restrict__ out,
    const float* __restrict__ g, const float* __restrict__ bb) {
  int row = blockIdx.x, t = threadIdx.x;
  float v = in[(size_t)row * D + t];
  float s = v, s2 = v * v;
#pragma unroll
  for (int o = 1; o < 64; o <<= 1) { s += __shfl_xor(s, o, 64); s2 += __shfl_xor(s2, o, 64); }
  __shared__ float rs[2], rs2[2];
  int w = t >> 6;
  if ((t & 63) == 0) { rs[w] = s; rs2[w] = s2; }
  __syncthreads();
  float S = rs[0] + rs[1], S2 = rs2[0] + rs2[1];
  float mu = S * (1.0f / D);
  float var = S2 * (1.0f / D) - mu * mu;
  float r = rsqrtf(var + EPS);
  out[(size_t)row * D + t] = (v - mu) * r * g[t] + bb[t];
}

// ---------------- batched relay matvecs: out[b*stride + n] = relay[b,:] @ W[n,:] + bias[n]
struct MVDesc { const float* W; const float* bias; float* out; int outStride; };
struct MVArgs { MVDesc d[3]; };
__global__ __launch_bounds__(128) void mv_batch(
    const float* __restrict__ relay, MVArgs ma) {
  int b = blockIdx.x;
  int di = blockIdx.y >> 2;
  int n = (blockIdx.y & 3) * 128 + threadIdx.x;
  __shared__ float as[D];
  as[threadIdx.x] = relay[(size_t)b * D + threadIdx.x];
  __syncthreads();
  MVDesc d = ma.d[di];
  float acc = d.bias[n];
  const float2* w2 = (const float2*)(d.W + (size_t)n * D);
  const float2* a2 = (const float2*)as;
#pragma unroll 8
  for (int i = 0; i < D / 2; i++) { float2 wv = w2[i], av = a2[i]; acc += av.x * wv.x + av.y * wv.y; }
  d.out[(size_t)b * d.outStride + n] = acc;
}

// ---------------- ring (windowed) attention, 5 kv entries per (b,l,head)
__global__ __launch_bounds__(256) void ring_attn_kernel(
    const float* __restrict__ q, const float* __restrict__ k, const float* __restrict__ v,
    const float* __restrict__ akr, const float* __restrict__ avr,
    const float* __restrict__ rk, const float* __restrict__ rv,
    float* __restrict__ att) {
  int bl = blockIdx.x;
  int b = bl >> 11, l = bl & (L - 1);
  int n = threadIdx.x >> 6, lane = threadIdx.x & 63;
  int h = lane << 1;
  size_t base = (size_t)bl * D2 + n * HD + h;
  float q0 = q[base], q1 = q[base + 1];
  float s[5], v0[5], v1[5];
#pragma unroll
  for (int u = 0; u < 5; u++) {
    float k0 = 0.f, k1 = 0.f, vv0 = 0.f, vv1 = 0.f;
    if (u < 3) {
      int ll = l + u - 1;
      if (ll >= 0 && ll < L) {
        size_t off = ((size_t)b * L + ll) * D2 + n * HD + h;
        k0 = k[off]; k1 = k[off + 1]; vv0 = v[off]; vv1 = v[off + 1];
      }
    } else if (u == 3) {
      k0 = akr[base]; k1 = akr[base + 1]; vv0 = avr[base]; vv1 = avr[base + 1];
    } else {
      size_t rb = (size_t)b * D2 + n * HD + h;
      k0 = rk[rb]; k1 = rk[rb + 1]; vv0 = rv[rb]; vv1 = rv[rb + 1];
    }
    float p = q0 * k0 + q1 * k1;
#pragma unroll
    for (int o = 1; o < 64; o <<= 1) p += __shfl_xor(p, o, 64);
    s[u] = p * SCALE;
    v0[u] = vv0; v1[u] = vv1;
  }
  float m = s[0];
#pragma unroll
  for (int u = 1; u < 5; u++) m = fmaxf(m, s[u]);
  float sum = 0.f, o0 = 0.f, o1 = 0.f;
#pragma unroll
  for (int u = 0; u < 5; u++) {
    float e = expf(s[u] - m);
    sum += e; o0 += e * v0[u]; o1 += e * v1[u];
  }
  att[base] = o0 / sum;
  att[base + 1] = o1 / sum;
}

// ---------------- relay attention, phase 1: per-(b,head,chunk) partial softmax
__global__ __launch_bounds__(256) void relay_attn_partial(
    const float* __restrict__ sq, const float* __restrict__ sk, const float* __restrict__ sv,
    const int* __restrict__ mask,
    float* __restrict__ pm, float* __restrict__ ps, float* __restrict__ po) {
  int bn = blockIdx.x;           // b*NH + n
  int b = bn >> 2, n = bn & 3;
  int c = blockIdx.y;
  int l0 = c * CHUNK;
  int nloc = min(CHUNK, L1 - l0);
  __shared__ float sqs[HD];
  __shared__ float sc[CHUNK];
  __shared__ float red[4];
  __shared__ float accs[2][HD];
  int t = threadIdx.x;
  if (t < HD) sqs[t] = sq[(size_t)b * D2 + n * HD + t];
  __syncthreads();
  int wv = t >> 6, lane = t & 63;
  float2 qv = ((const float2*)sqs)[lane];
  for (int i = wv; i < nloc; i += 4) {
    int l = l0 + i;
    float2 kk = ((const float2*)(sk + ((size_t)b * L1 + l) * D2 + n * HD))[lane];
    float s = qv.x * kk.x + qv.y * kk.y;
#pragma unroll
    for (int o = 1; o < 64; o <<= 1) s += __shfl_xor(s, o, 64);
    if (lane == 0) {
      s *= SCALE;
      if (l > 0 && mask[b * L + l - 1] == 0) s = -1e30f;
      sc[i] = s;
    }
  }
  __syncthreads();
  float m = -1e30f;
  for (int i = t; i < nloc; i += 256) m = fmaxf(m, sc[i]);
#pragma unroll
  for (int o = 1; o < 64; o <<= 1) m = fmaxf(m, __shfl_xor(m, o, 64));
  if (lane == 0) red[wv] = m;
  __syncthreads();
  m = fmaxf(fmaxf(red[0], red[1]), fmaxf(red[2], red[3]));
  __syncthreads();
  float sum = 0.f;
  for (int i = t; i < nloc; i += 256) { float e = expf(sc[i] - m); sc[i] = e; sum += e; }
#pragma unroll
  for (int o = 1; o < 64; o <<= 1) sum += __shfl_xor(sum, o, 64);
  if (lane == 0) red[wv] = sum;
  __syncthreads();
  sum = red[0] + red[1] + red[2] + red[3];
  int h = t & 127, p = t >> 7;
  float o = 0.f;
  for (int i = p; i < nloc; i += 2)
    o += sc[i] * sv[((size_t)b * L1 + l0 + i) * D2 + n * HD + h];
  accs[p][h] = o;
  __syncthreads();
  if (t < HD) po[((size_t)bn * NCH + c) * HD + t] = accs[0][t] + accs[1][t];
  if (t == 0) { pm[bn * NCH + c] = m; ps[bn * NCH + c] = sum; }
}

// ---------------- combine partials + relay = leaky(satt @ so_w.T + so_b)
__global__ __launch_bounds__(128) void relay_finalize(
    const float* __restrict__ pm, const float* __restrict__ ps, const float* __restrict__ po,
    const float* __restrict__ so_w, const float* __restrict__ so_b,
    float* __restrict__ out) {
  int b = blockIdx.x, t = threadIdx.x;
  __shared__ float satts[D2];
#pragma unroll
  for (int n = 0; n < NH; n++) {
    int bn = b * NH + n;
    float M = -1e30f;
#pragma unroll
    for (int c = 0; c < NCH; c++) M = fmaxf(M, pm[bn * NCH + c]);
    float S = 0.f, O = 0.f;
#pragma unroll
    for (int c = 0; c < NCH; c++) {
      float w = expf(pm[bn * NCH + c] - M);
      S += ps[bn * NCH + c] * w;
      O += po[((size_t)bn * NCH + c) * HD + t] * w;
    }
    satts[n * HD + t] = O / S;
  }
  __syncthreads();
  float acc = so_b[t];
  const float2* w2 = (const float2*)(so_w + (size_t)t * D2);
  const float2* a2 = (const float2*)satts;
#pragma unroll 8
  for (int i = 0; i < D2 / 2; i++) { float2 wv = w2[i], av = a2[i]; acc += av.x * wv.x + av.y * wv.y; }
  acc = (acc > 0.f) ? acc : 0.01f * acc;
  out[(size_t)b * D + t] = acc;
}

extern "C" void kernel_launch(void* const* d_in, const int* in_sizes, int n_in,
                              void* d_out, int out_size, void* d_ws, size_t ws_size,
                              hipStream_t stream) {
  const int* tokens = (const int*)d_in[0];
  const int* mask = (const int*)d_in[1];
  const float* emb = (const float*)d_in[2];
  const float* proj_w = (const float*)d_in[3];
  const float* proj_b = (const float*)d_in[4];
  const float* ng = (const float*)d_in[5];
  const float* nb = (const float*)d_in[6];
  const float* rq_w = (const float*)d_in[7], * rq_b = (const float*)d_in[8];
  const float* rk_w = (const float*)d_in[9], * rk_b = (const float*)d_in[10];
  const float* rv_w = (const float*)d_in[11], * rv_b = (const float*)d_in[12];
  const float* ro_w = (const float*)d_in[13], * ro_b = (const float*)d_in[14];
  const float* sq_w = (const float*)d_in[15], * sq_b = (const float*)d_in[16];
  const float* sk_w = (const float*)d_in[17], * sk_b = (const float*)d_in[18];
  const float* sv_w = (const float*)d_in[19], * sv_b = (const float*)d_in[20];
  const float* so_w = (const float*)d_in[21], * so_b = (const float*)d_in[22];

  float* ws = (float*)d_ws;
  const size_t BLD = (size_t)B * L * D;       // 1,048,576
  const size_t SLOT = (size_t)B * L1 * D2;    // 4,196,352
  float* x = ws;
  float* nodes = x + BLD;
  float* nx = nodes + BLD;
  float* relay = nx + BLD;
  float* relay_k = relay + B * D;
  float* relay_v = relay_k + B * D2;
  float* sqv = relay_v + B * D2;
  float* slot0 = sqv + B * D2;    // q, later sk
  float* slot1 = slot0 + SLOT;    // k, later sv
  float* slot2 = slot1 + SLOT;    // v
  float* slot3 = slot2 + SLOT;    // ak (r_embs)
  float* slot4 = slot3 + SLOT;    // av (r_embs)
  float* slot5 = slot4 + SLOT;    // att
  float* pm = slot5 + SLOT;       // [B*NH, NCH]
  float* ps = pm + B * NH * NCH;
  float* po = ps + B * NH * NCH;  // [B*NH, NCH, HD]

  hipMemsetAsync(relay, 0, B * D * sizeof(float), stream);

  // embedding projection as gathered-A MFMA GEMM: [8192,300] @ [128,300]^T
  {
    GArgs ga = {};
    ga.d[0].A = emb; ga.d[0].W = proj_w; ga.d[0].bias = proj_b;
    ga.d[0].out = x; ga.d[0].out2 = nodes; ga.d[0].gather = tokens;
    gemm_mfma<<<dim3(128, 2), 256, 0, stream>>>(ga, 2, D, E);
  }
  relay_init_kernel<<<B * 64, 128, 0, stream>>>(x, relay);

  for (int i = 0; i < NL; i++) {
    const float* rqwi = rq_w + (size_t)i * D2 * D, * rqbi = rq_b + (size_t)i * D2;
    const float* rkwi = rk_w + (size_t)i * D2 * D, * rkbi = rk_b + (size_t)i * D2;
    const float* rvwi = rv_w + (size_t)i * D2 * D, * rvbi = rv_b + (size_t)i * D2;
    const float* rowi = ro_w + (size_t)i * D * D2, * robi = ro_b + (size_t)i * D;
    const float* sqwi = sq_w + (size_t)i * D2 * D, * sqbi = sq_b + (size_t)i * D2;
    const float* skwi = sk_w + (size_t)i * D2 * D, * skbi = sk_b + (size_t)i * D2;
    const float* svwi = sv_w + (size_t)i * D2 * D, * svbi = sv_b + (size_t)i * D2;
    const float* sowi = so_w + (size_t)i * D * D2, * sobi = so_b + (size_t)i * D;

    ln_kernel<<<B * L, 128, 0, stream>>>(nodes, nx, ng + i * D, nb + i * D);

    // fused q,k,v (from nx) + ak,av (from x): one dispatch, 5120 blocks
    {
      GArgs ga = {};
      ga.d[0].A = nx; ga.d[0].W = rqwi; ga.d[0].bias = rqbi; ga.d[0].out = slot0;
      ga.d[1].A = nx; ga.d[1].W = rkwi; ga.d[1].bias = rkbi; ga.d[1].out = slot1;
      ga.d[2].A = nx; ga.d[2].W = rvwi; ga.d[2].bias = rvbi; ga.d[2].out = slot2;
      ga.d[3].A = x;  ga.d[3].W = rkwi; ga.d[3].bias = rkbi; ga.d[3].out = slot3;
      ga.d[4].A = x;  ga.d[4].W = rvwi; ga.d[4].bias = rvbi; ga.d[4].out = slot4;
      gemm_mfma<<<dim3(128, 40), 256, 0, stream>>>(ga, 8, D2, D);
    }
    // relay-row projections needed before/at ring + relay attention: rk, rv, sq
    {
      MVArgs ma = {};
      ma.d[0] = {rkwi, rkbi, relay_k, D2};
      ma.d[1] = {rvwi, rvbi, relay_v, D2};
      ma.d[2] = {sqwi, sqbi, sqv, D2};
      mv_batch<<<dim3(B, 12), 128, 0, stream>>>(relay, ma);
    }
    ring_attn_kernel<<<B * L, 256, 0, stream>>>(slot0, slot1, slot2, slot3, slot4, relay_k, relay_v, slot5);
    // nodes = where(pad, 0, nodes + leaky_relu(att @ ro_w.T + ro_b))  [mask folded in]
    {
      GArgs ga = {};
      ga.d[0].A = slot5; ga.d[0].W = rowi; ga.d[0].bias = robi;
      ga.d[0].out = nodes; ga.d[0].resid = nodes; ga.d[0].mask = mask; ga.d[0].residleaky = 1;
      gemm_mfma<<<dim3(128, 2), 256, 0, stream>>>(ga, 2, D, D2);
    }
    // MSA2: sk, sv over nodes (rows 1.. of [B,L1,D2])
    {
      GArgs ga = {};
      ga.d[0].A = nodes; ga.d[0].W = skwi; ga.d[0].bias = skbi; ga.d[0].out = slot0; ga.d[0].relayrows = 1;
      ga.d[1].A = nodes; ga.d[1].W = svwi; ga.d[1].bias = svbi; ga.d[1].out = slot1; ga.d[1].relayrows = 1;
      gemm_mfma<<<dim3(128, 16), 256, 0, stream>>>(ga, 8, D2, D);
    }
    // relay rows (row 0 per batch) of sk/sv
    {
      MVArgs ma = {};
      ma.d[0] = {skwi, skbi, slot0, L1 * D2};
      ma.d[1] = {svwi, svbi, slot1, L1 * D2};
      ma.d[2] = {skwi, skbi, relay_k, D2};  // dummy-safe: overwritten next layer (keeps grid uniform)
      mv_batch<<<dim3(B, 8), 128, 0, stream>>>(relay, ma);  // grid.y=8 -> only d[0],d[1] used
    }
    relay_attn_partial<<<dim3(B * NH, NCH), 256, 0, stream>>>(sqv, slot0, slot1, mask, pm, ps, po);
    // combine + relay = leaky_relu(satt @ so_w.T + so_b); last layer -> d_out
    float* relay_dst = (i == NL - 1) ? (float*)d_out : relay;
    relay_finalize<<<B, 128, 0, stream>>>(pm, ps, po, sowi, sobi, relay_dst);
  }
}

// Round 6
// 479.386 us; speedup vs baseline: 3.9291x; 1.3591x over previous
//
#include <hip/hip_runtime.h>
#include <hip/hip_bf16.h>

// Problem constants
constexpr int B = 4, L = 2048, E = 300, D = 128, NH = 4, HD = 128, NL = 3, D2 = 512;
constexpr int L1 = L + 1; // 2049
constexpr float EPS = 1e-5f;
constexpr float SCALE = 0.08838834764831843f; // 1/sqrt(128)
constexpr int NCH = 32;              // relay-attention L-chunks
constexpr int CHUNK = 65;            // ceil(2049/32)

typedef unsigned int uint_t;
typedef unsigned short u16;
typedef short bf16x8 __attribute__((ext_vector_type(8)));
typedef float f32x4 __attribute__((ext_vector_type(4)));

__device__ __forceinline__ u16 f2bf(float f) {
  union { float f; uint_t i; } x; x.f = f;
  uint_t r = x.i + 0x7fffu + ((x.i >> 16) & 1u);
  return (u16)(r >> 16);
}
__device__ __forceinline__ uint_t packbf(float a, float b) {
  return (uint_t)f2bf(a) | ((uint_t)f2bf(b) << 16);
}
__device__ __forceinline__ float bf2f(u16 u) {
  union { uint_t i; float f; } x; x.i = ((uint_t)u) << 16; return x.f;
}
__device__ __forceinline__ float2 bf2x2(uint_t u) {
  union { uint_t i; float f; } a, b;
  a.i = (u & 0xffffu) << 16; b.i = u & 0xffff0000u;
  return make_float2(a.f, b.f);
}

// ---------------- weight pre-conversion: 8 tensors, each NL*D*D2 fp32 -> bf16
struct WCArgs { const float* s[8]; u16* d[8]; };
__global__ __launch_bounds__(256) void wconv(WCArgs wa) {
  int ti = blockIdx.y;
  const float* s = wa.s[ti]; u16* dd = wa.d[ti];
  int i = (blockIdx.x * 256 + threadIdx.x) * 4;  // covers NL*D*D2 = 196608 exactly
  float4 f = *(const float4*)(s + i);
  *(uint2*)(dd + i) = make_uint2(packbf(f.x, f.y), packbf(f.z, f.w));
}

// ================= all-bf16 MFMA GEMM: out[M,N] = A[M,K] @ W[N,K]^T + bias
// 64x64 tile, BK=64, 256 threads = 4 waves 2x2 (each 32x32).
struct GDesc {
  const u16* A; const u16* W; const float* bias;
  u16* outb;                // bf16 output (when !residleaky)
  float* outf;              // fp32 output (residleaky path)
  const float* resid; u16* out2b; const int* mask;
  int relayrows, residleaky;
};
struct GArgs { GDesc d[5]; };

__global__ __launch_bounds__(256) void gemm_bf(GArgs ga, int nby, int N, int K) {
  __shared__ u16 As[64][72];
  __shared__ u16 Ws[64][72];
  int t = threadIdx.x;
  int bm = blockIdx.x;
  int di = blockIdx.y / nby, bn = blockIdx.y - di * nby;
  GDesc d = ga.d[di];
  const int rowA = bm * 64, rowW = bn * 64;

  f32x4 acc[2][2];
#pragma unroll
  for (int i = 0; i < 2; i++)
#pragma unroll
    for (int j = 0; j < 2; j++)
      acc[i][j] = (f32x4){0.f, 0.f, 0.f, 0.f};

  const int r = t >> 2;             // 0..63
  const int c0 = (t & 3) * 16;      // 0,16,32,48 (shorts)
  const int wid = t >> 6;
  const int wm = (wid & 1) * 32, wn = (wid >> 1) * 32;
  const int lr = t & 15, quad = (t >> 4) & 3;

  const u16* Arow = d.A + (size_t)(rowA + r) * K;
  const u16* Wrow = d.W + (size_t)(rowW + r) * K;

  for (int kt = 0; kt < K; kt += 64) {
    uint4 a0 = *(const uint4*)(Arow + kt + c0);
    uint4 a1 = *(const uint4*)(Arow + kt + c0 + 8);
    uint4 w0 = *(const uint4*)(Wrow + kt + c0);
    uint4 w1 = *(const uint4*)(Wrow + kt + c0 + 8);
    __syncthreads();
    *(uint4*)&As[r][c0] = a0; *(uint4*)&As[r][c0 + 8] = a1;
    *(uint4*)&Ws[r][c0] = w0; *(uint4*)&Ws[r][c0 + 8] = w1;
    __syncthreads();
#pragma unroll
    for (int ks = 0; ks < 2; ks++) {
      bf16x8 af[2], bfr[2];
#pragma unroll
      for (int mt = 0; mt < 2; mt++)
        af[mt] = *(const bf16x8*)&As[wm + mt * 16 + lr][ks * 32 + quad * 8];
#pragma unroll
      for (int nt = 0; nt < 2; nt++)
        bfr[nt] = *(const bf16x8*)&Ws[wn + nt * 16 + lr][ks * 32 + quad * 8];
#pragma unroll
      for (int mt = 0; mt < 2; mt++)
#pragma unroll
        for (int nt = 0; nt < 2; nt++)
          acc[mt][nt] = __builtin_amdgcn_mfma_f32_16x16x32_bf16(af[mt], bfr[nt], acc[mt][nt], 0, 0, 0);
    }
  }

  // epilogue: C/D layout col=lane&15, row=quad*4+reg
#pragma unroll
  for (int nt = 0; nt < 2; nt++) {
    int col = rowW + wn + nt * 16 + lr;
    float bv = d.bias[col];
#pragma unroll
    for (int mt = 0; mt < 2; mt++) {
#pragma unroll
      for (int rr = 0; rr < 4; rr++) {
        int row = rowA + wm + mt * 16 + quad * 4 + rr;
        float v = acc[mt][nt][rr] + bv;
        if (d.residleaky) {
          v = (v > 0.f) ? v : 0.01f * v;
          v += d.resid[(size_t)row * N + col];
          if (d.mask && d.mask[row] == 0) v = 0.f;
          d.outf[(size_t)row * N + col] = v;
          d.out2b[(size_t)row * N + col] = f2bf(v);
        } else {
          int orow = d.relayrows ? row + (row >> 11) + 1 : row;  // row/L + 1
          d.outb[(size_t)orow * N + col] = f2bf(v);
        }
      }
    }
  }
}

// ================= fp32-input MFMA GEMM for the embedding projection (gathered A, K=300)
__global__ __launch_bounds__(256) void gemm_embed(
    const float* __restrict__ A, const float* __restrict__ W, const float* __restrict__ bias,
    float* __restrict__ outf, u16* __restrict__ outb,
    const int* __restrict__ gather, int N, int K) {
  __shared__ u16 As[64][72];
  __shared__ u16 Ws[64][72];
  int t = threadIdx.x;
  int bm = blockIdx.x, bn = blockIdx.y;
  const int rowA = bm * 64, rowW = bn * 64;

  f32x4 acc[2][2];
#pragma unroll
  for (int i = 0; i < 2; i++)
#pragma unroll
    for (int j = 0; j < 2; j++)
      acc[i][j] = (f32x4){0.f, 0.f, 0.f, 0.f};

  const int srow = t >> 2, sc0 = (t & 3) * 16;
  const int wid = t >> 6, wm = (wid & 1) * 32, wn = (wid >> 1) * 32;
  const int lr = t & 15, quad = (t >> 4) & 3;

  const float* Arow = A + (size_t)gather[rowA + srow] * K;
  const float* Wrow = W + (size_t)(rowW + srow) * K;

  for (int kt = 0; kt < K; kt += 64) {
    __syncthreads();
    bool full = (kt + 64 <= K);
#pragma unroll
    for (int ch = 0; ch < 4; ch++) {
      int c = kt + sc0 + ch * 4;
      float4 fa, fw;
      if (full) {
        fa = *(const float4*)(Arow + c);
        fw = *(const float4*)(Wrow + c);
      } else {
        fa.x = (c + 0 < K) ? Arow[c + 0] : 0.f;
        fa.y = (c + 1 < K) ? Arow[c + 1] : 0.f;
        fa.z = (c + 2 < K) ? Arow[c + 2] : 0.f;
        fa.w = (c + 3 < K) ? Arow[c + 3] : 0.f;
        fw.x = (c + 0 < K) ? Wrow[c + 0] : 0.f;
        fw.y = (c + 1 < K) ? Wrow[c + 1] : 0.f;
        fw.z = (c + 2 < K) ? Wrow[c + 2] : 0.f;
        fw.w = (c + 3 < K) ? Wrow[c + 3] : 0.f;
      }
      *(uint2*)&As[srow][sc0 + ch * 4] = make_uint2(packbf(fa.x, fa.y), packbf(fa.z, fa.w));
      *(uint2*)&Ws[srow][sc0 + ch * 4] = make_uint2(packbf(fw.x, fw.y), packbf(fw.z, fw.w));
    }
    __syncthreads();
#pragma unroll
    for (int ks = 0; ks < 2; ks++) {
      bf16x8 af[2], bfr[2];
#pragma unroll
      for (int mt = 0; mt < 2; mt++)
        af[mt] = *(const bf16x8*)&As[wm + mt * 16 + lr][ks * 32 + quad * 8];
#pragma unroll
      for (int nt = 0; nt < 2; nt++)
        bfr[nt] = *(const bf16x8*)&Ws[wn + nt * 16 + lr][ks * 32 + quad * 8];
#pragma unroll
      for (int mt = 0; mt < 2; mt++)
#pragma unroll
        for (int nt = 0; nt < 2; nt++)
          acc[mt][nt] = __builtin_amdgcn_mfma_f32_16x16x32_bf16(af[mt], bfr[nt], acc[mt][nt], 0, 0, 0);
    }
  }
#pragma unroll
  for (int nt = 0; nt < 2; nt++) {
    int col = rowW + wn + nt * 16 + lr;
    float bv = bias[col];
#pragma unroll
    for (int mt = 0; mt < 2; mt++) {
#pragma unroll
      for (int rr = 0; rr < 4; rr++) {
        int row = rowA + wm + mt * 16 + quad * 4 + rr;
        float v = acc[mt][nt][rr] + bv;
        outf[(size_t)row * N + col] = v;   // nodes (fp32)
        outb[(size_t)row * N + col] = f2bf(v);  // xb (bf16)
      }
    }
  }
}

// ---------------- relay = mean over L of nodes  (relay zeroed first)
__global__ __launch_bounds__(128) void relay_init_kernel(const float* __restrict__ x, float* __restrict__ relay) {
  int b = blockIdx.x >> 6, c = blockIdx.x & 63, t = threadIdx.x;
  float sum = 0.f;
  for (int i = 0; i < 32; i++) {
    int l = c * 32 + i;
    sum += x[((size_t)b * L + l) * D + t];
  }
  atomicAdd(&relay[b * D + t], sum * (1.0f / L));
}

// ---------------- layernorm (fp32 in, bf16 out)
__global__ __launch_bounds__(128) void ln_kernel(
    const float* __restrict__ in, u16* __restrict__ out,
    const float* __restrict__ g, const float* __restrict__ bb) {
  int row = blockIdx.x, t = threadIdx.x;
  float v = in[(size_t)row * D + t];
  float s = v, s2 = v * v;
#pragma unroll
  for (int o = 1; o < 64; o <<= 1) { s += __shfl_xor(s, o, 64); s2 += __shfl_xor(s2, o, 64); }
  __shared__ float rs[2], rs2[2];
  int w = t >> 6;
  if ((t & 63) == 0) { rs[w] = s; rs2[w] = s2; }
  __syncthreads();
  float S = rs[0] + rs[1], S2 = rs2[0] + rs2[1];
  float mu = S * (1.0f / D);
  float var = S2 * (1.0f / D) - mu * mu;
  float r = rsqrtf(var + EPS);
  out[(size_t)row * D + t] = f2bf((v - mu) * r * g[t] + bb[t]);
}

// ---------------- batched relay matvecs (fp32 relay, fp32 weights)
struct MVDesc { const float* W; const float* bias; void* out; int outStride; int bf16out; };
struct MVArgs { MVDesc d[3]; };
__global__ __launch_bounds__(128) void mv_batch(
    const float* __restrict__ relay, MVArgs ma) {
  int b = blockIdx.x;
  int di = blockIdx.y >> 2;
  int n = (blockIdx.y & 3) * 128 + threadIdx.x;
  __shared__ float as[D];
  as[threadIdx.x] = relay[(size_t)b * D + threadIdx.x];
  __syncthreads();
  MVDesc d = ma.d[di];
  float acc = d.bias[n];
  const float2* w2 = (const float2*)(d.W + (size_t)n * D);
  const float2* a2 = (const float2*)as;
#pragma unroll 8
  for (int i = 0; i < D / 2; i++) { float2 wv = w2[i], av = a2[i]; acc += av.x * wv.x + av.y * wv.y; }
  if (d.bf16out) ((u16*)d.out)[(size_t)b * d.outStride + n] = f2bf(acc);
  else ((float*)d.out)[(size_t)b * d.outStride + n] = acc;
}

// ---------------- ring (windowed) attention; bf16 q/k/v/ak/av + att, fp32 rk/rv
__global__ __launch_bounds__(256) void ring_attn_kernel(
    const u16* __restrict__ q, const u16* __restrict__ k, const u16* __restrict__ v,
    const u16* __restrict__ akr, const u16* __restrict__ avr,
    const float* __restrict__ rk, const float* __restrict__ rv,
    u16* __restrict__ att) {
  int bl = blockIdx.x;
  int b = bl >> 11, l = bl & (L - 1);
  int n = threadIdx.x >> 6, lane = threadIdx.x & 63;
  int h = lane << 1;
  size_t base = (size_t)bl * D2 + n * HD + h;
  float2 qv = bf2x2(*(const uint_t*)(q + base));
  float s[5], v0[5], v1[5];
#pragma unroll
  for (int u = 0; u < 5; u++) {
    float k0 = 0.f, k1 = 0.f, vv0 = 0.f, vv1 = 0.f;
    if (u < 3) {
      int ll = l + u - 1;
      if (ll >= 0 && ll < L) {
        size_t off = ((size_t)b * L + ll) * D2 + n * HD + h;
        float2 kf = bf2x2(*(const uint_t*)(k + off));
        float2 vf = bf2x2(*(const uint_t*)(v + off));
        k0 = kf.x; k1 = kf.y; vv0 = vf.x; vv1 = vf.y;
      }
    } else if (u == 3) {
      float2 kf = bf2x2(*(const uint_t*)(akr + base));
      float2 vf = bf2x2(*(const uint_t*)(avr + base));
      k0 = kf.x; k1 = kf.y; vv0 = vf.x; vv1 = vf.y;
    } else {
      size_t rb = (size_t)b * D2 + n * HD + h;
      k0 = rk[rb]; k1 = rk[rb + 1]; vv0 = rv[rb]; vv1 = rv[rb + 1];
    }
    float p = qv.x * k0 + qv.y * k1;
#pragma unroll
    for (int o = 1; o < 64; o <<= 1) p += __shfl_xor(p, o, 64);
    s[u] = p * SCALE;
    v0[u] = vv0; v1[u] = vv1;
  }
  float m = s[0];
#pragma unroll
  for (int u = 1; u < 5; u++) m = fmaxf(m, s[u]);
  float sum = 0.f, o0 = 0.f, o1 = 0.f;
#pragma unroll
  for (int u = 0; u < 5; u++) {
    float e = expf(s[u] - m);
    sum += e; o0 += e * v0[u]; o1 += e * v1[u];
  }
  *(uint_t*)(att + base) = packbf(o0 / sum, o1 / sum);
}

// ---------------- relay attention phase 1 (bf16 sk/sv, fp32 sq)
__global__ __launch_bounds__(256) void relay_attn_partial(
    const float* __restrict__ sq, const u16* __restrict__ sk, const u16* __restrict__ sv,
    const int* __restrict__ mask,
    float* __restrict__ pm, float* __restrict__ ps, float* __restrict__ po) {
  int bn = blockIdx.x;           // b*NH + n
  int b = bn >> 2, n = bn & 3;
  int c = blockIdx.y;
  int l0 = c * CHUNK;
  int nloc = min(CHUNK, L1 - l0);
  __shared__ float sqs[HD];
  __shared__ float sc[CHUNK];
  __shared__ float red[4];
  __shared__ float accs[2][HD];
  int t = threadIdx.x;
  if (t < HD) sqs[t] = sq[(size_t)b * D2 + n * HD + t];
  __syncthreads();
  int wv = t >> 6, lane = t & 63;
  float2 qv = ((const float2*)sqs)[lane];
  for (int i = wv; i < nloc; i += 4) {
    int l = l0 + i;
    float2 kk = bf2x2(*(const uint_t*)(sk + ((size_t)b * L1 + l) * D2 + n * HD + 2 * lane));
    float s = qv.x * kk.x + qv.y * kk.y;
#pragma unroll
    for (int o = 1; o < 64; o <<= 1) s += __shfl_xor(s, o, 64);
    if (lane == 0) {
      s *= SCALE;
      if (l > 0 && mask[b * L + l - 1] == 0) s = -1e30f;
      sc[i] = s;
    }
  }
  __syncthreads();
  float m = -1e30f;
  for (int i = t; i < nloc; i += 256) m = fmaxf(m, sc[i]);
#pragma unroll
  for (int o = 1; o < 64; o <<= 1) m = fmaxf(m, __shfl_xor(m, o, 64));
  if (lane == 0) red[wv] = m;
  __syncthreads();
  m = fmaxf(fmaxf(red[0], red[1]), fmaxf(red[2], red[3]));
  __syncthreads();
  float sum = 0.f;
  for (int i = t; i < nloc; i += 256) { float e = expf(sc[i] - m); sc[i] = e; sum += e; }
#pragma unroll
  for (int o = 1; o < 64; o <<= 1) sum += __shfl_xor(sum, o, 64);
  if (lane == 0) red[wv] = sum;
  __syncthreads();
  sum = red[0] + red[1] + red[2] + red[3];
  int h = t & 127, p = t >> 7;
  float o = 0.f;
  for (int i = p; i < nloc; i += 2)
    o += sc[i] * bf2f(sv[((size_t)b * L1 + l0 + i) * D2 + n * HD + h]);
  accs[p][h] = o;
  __syncthreads();
  if (t < HD) po[((size_t)bn * NCH + c) * HD + t] = accs[0][t] + accs[1][t];
  if (t == 0) { pm[bn * NCH + c] = m; ps[bn * NCH + c] = sum; }
}

// ---------------- combine partials + relay = leaky(satt @ so_w.T + so_b)
__global__ __launch_bounds__(128) void relay_finalize(
    const float* __restrict__ pm, const float* __restrict__ ps, const float* __restrict__ po,
    const float* __restrict__ so_w, const float* __restrict__ so_b,
    float* __restrict__ out) {
  int b = blockIdx.x, t = threadIdx.x;
  __shared__ float satts[D2];
#pragma unroll
  for (int n = 0; n < NH; n++) {
    int bn = b * NH + n;
    float M = -1e30f;
#pragma unroll
    for (int c = 0; c < NCH; c++) M = fmaxf(M, pm[bn * NCH + c]);
    float S = 0.f, O = 0.f;
#pragma unroll
    for (int c = 0; c < NCH; c++) {
      float w = expf(pm[bn * NCH + c] - M);
      S += ps[bn * NCH + c] * w;
      O += po[((size_t)bn * NCH + c) * HD + t] * w;
    }
    satts[n * HD + t] = O / S;
  }
  __syncthreads();
  float acc = so_b[t];
  const float2* w2 = (const float2*)(so_w + (size_t)t * D2);
  const float2* a2 = (const float2*)satts;
#pragma unroll 8
  for (int i = 0; i < D2 / 2; i++) { float2 wv = w2[i], av = a2[i]; acc += av.x * wv.x + av.y * wv.y; }
  acc = (acc > 0.f) ? acc : 0.01f * acc;
  out[(size_t)b * D + t] = acc;
}

extern "C" void kernel_launch(void* const* d_in, const int* in_sizes, int n_in,
                              void* d_out, int out_size, void* d_ws, size_t ws_size,
                              hipStream_t stream) {
  const int* tokens = (const int*)d_in[0];
  const int* mask = (const int*)d_in[1];
  const float* emb = (const float*)d_in[2];
  const float* proj_w = (const float*)d_in[3];
  const float* proj_b = (const float*)d_in[4];
  const float* ng = (const float*)d_in[5];
  const float* nb = (const float*)d_in[6];
  const float* rq_w = (const float*)d_in[7], * rq_b = (const float*)d_in[8];
  const float* rk_w = (const float*)d_in[9], * rk_b = (const float*)d_in[10];
  const float* rv_w = (const float*)d_in[11], * rv_b = (const float*)d_in[12];
  const float* ro_w = (const float*)d_in[13], * ro_b = (const float*)d_in[14];
  const float* sq_w = (const float*)d_in[15], * sq_b = (const float*)d_in[16];
  const float* sk_w = (const float*)d_in[17], * sk_b = (const float*)d_in[18];
  const float* sv_w = (const float*)d_in[19], * sv_b = (const float*)d_in[20];
  const float* so_w = (const float*)d_in[21], * so_b = (const float*)d_in[22];

  const size_t BLD = (size_t)B * L * D;        // 1,048,576
  const size_t BLD4 = (size_t)B * L * D2;      // 4,194,304
  const size_t SLOT = (size_t)B * L1 * D2;     // 4,196,352
  const size_t WTEN = (size_t)NL * D * D2;     // 196,608 per tensor

  float* fp = (float*)d_ws;
  float* nodes = fp;                    fp += BLD;
  float* relay = fp;                    fp += B * D;
  float* relay_k = fp;                  fp += B * D2;
  float* relay_v = fp;                  fp += B * D2;
  float* sqv = fp;                      fp += B * D2;
  float* pm = fp;                       fp += B * NH * NCH;
  float* ps = fp;                       fp += B * NH * NCH;
  float* po = fp;                       fp += (size_t)B * NH * NCH * HD;
  u16* up = (u16*)fp;
  u16* xb = up;                         up += BLD;
  u16* nxb = up;                        up += BLD;
  u16* nodesb = up;                     up += BLD;
  u16* qb = up;                         up += BLD4;
  u16* kb = up;                         up += BLD4;
  u16* vb = up;                         up += BLD4;
  u16* akb = up;                        up += BLD4;
  u16* avb = up;                        up += BLD4;
  u16* attb = up;                       up += BLD4;
  u16* skb = up;                        up += SLOT;
  u16* svb = up;                        up += SLOT;
  u16* wb = up;                         // 8 * WTEN
  u16* wrq = wb, * wrk = wb + WTEN, * wrv = wb + 2 * WTEN, * wro = wb + 3 * WTEN;
  u16* wsq = wb + 4 * WTEN, * wsk = wb + 5 * WTEN, * wsv = wb + 6 * WTEN, * wso = wb + 7 * WTEN;

  hipMemsetAsync(relay, 0, B * D * sizeof(float), stream);

  // convert weights to bf16 (one-time per launch)
  {
    WCArgs wa;
    wa.s[0] = rq_w; wa.s[1] = rk_w; wa.s[2] = rv_w; wa.s[3] = ro_w;
    wa.s[4] = sq_w; wa.s[5] = sk_w; wa.s[6] = sv_w; wa.s[7] = so_w;
    wa.d[0] = wrq; wa.d[1] = wrk; wa.d[2] = wrv; wa.d[3] = wro;
    wa.d[4] = wsq; wa.d[5] = wsk; wa.d[6] = wsv; wa.d[7] = wso;
    wconv<<<dim3(WTEN / 1024, 8), 256, 0, stream>>>(wa);
  }
  // embedding projection: nodes (fp32) + xb (bf16)
  gemm_embed<<<dim3(128, 2), 256, 0, stream>>>(emb, proj_w, proj_b, nodes, xb, tokens, D, E);
  relay_init_kernel<<<B * 64, 128, 0, stream>>>(nodes, relay);

  for (int i = 0; i < NL; i++) {
    const float* rkwi = rk_w + (size_t)i * D2 * D, * rkbi = rk_b + (size_t)i * D2;
    const float* rvwi = rv_w + (size_t)i * D2 * D, * rvbi = rv_b + (size_t)i * D2;
    const float* rqbi = rq_b + (size_t)i * D2;
    const float* robi = ro_b + (size_t)i * D;
    const float* sqwi = sq_w + (size_t)i * D2 * D, * sqbi = sq_b + (size_t)i * D2;
    const float* skwi = sk_w + (size_t)i * D2 * D, * skbi = sk_b + (size_t)i * D2;
    const float* svwi = sv_w + (size_t)i * D2 * D, * svbi = sv_b + (size_t)i * D2;
    const float* sobi = so_b + (size_t)i * D;
    const size_t wo = (size_t)i * D * D2;

    ln_kernel<<<B * L, 128, 0, stream>>>(nodes, nxb, ng + i * D, nb + i * D);

    // fused q,k,v (from nxb) + ak,av (from xb): one dispatch
    {
      GArgs ga = {};
      ga.d[0].A = nxb; ga.d[0].W = wrq + wo; ga.d[0].bias = rqbi; ga.d[0].outb = qb;
      ga.d[1].A = nxb; ga.d[1].W = wrk + wo; ga.d[1].bias = rkbi; ga.d[1].outb = kb;
      ga.d[2].A = nxb; ga.d[2].W = wrv + wo; ga.d[2].bias = rvbi; ga.d[2].outb = vb;
      ga.d[3].A = xb;  ga.d[3].W = wrk + wo; ga.d[3].bias = rkbi; ga.d[3].outb = akb;
      ga.d[4].A = xb;  ga.d[4].W = wrv + wo; ga.d[4].bias = rvbi; ga.d[4].outb = avb;
      gemm_bf<<<dim3(128, 40), 256, 0, stream>>>(ga, 8, D2, D);
    }
    // relay-row projections: rk, rv (fp32), sq (fp32)
    {
      MVArgs ma = {};
      ma.d[0] = {rkwi, rkbi, relay_k, D2, 0};
      ma.d[1] = {rvwi, rvbi, relay_v, D2, 0};
      ma.d[2] = {sqwi, sqbi, sqv, D2, 0};
      mv_batch<<<dim3(B, 12), 128, 0, stream>>>(relay, ma);
    }
    ring_attn_kernel<<<B * L, 256, 0, stream>>>(qb, kb, vb, akb, avb, relay_k, relay_v, attb);
    // nodes = where(pad, 0, nodes + leaky(att @ ro^T + ro_b)); also nodesb (bf16)
    {
      GArgs ga = {};
      ga.d[0].A = attb; ga.d[0].W = wro + wo; ga.d[0].bias = robi;
      ga.d[0].outf = nodes; ga.d[0].resid = nodes; ga.d[0].out2b = nodesb;
      ga.d[0].mask = mask; ga.d[0].residleaky = 1;
      gemm_bf<<<dim3(128, 2), 256, 0, stream>>>(ga, 2, D, D2);
    }
    // MSA2: sk, sv over nodesb -> rows 1.. of [B,L1,D2] (bf16)
    {
      GArgs ga = {};
      ga.d[0].A = nodesb; ga.d[0].W = wsk + wo; ga.d[0].bias = skbi; ga.d[0].outb = skb; ga.d[0].relayrows = 1;
      ga.d[1].A = nodesb; ga.d[1].W = wsv + wo; ga.d[1].bias = svbi; ga.d[1].outb = svb; ga.d[1].relayrows = 1;
      gemm_bf<<<dim3(128, 16), 256, 0, stream>>>(ga, 8, D2, D);
    }
    // relay rows (row 0) of sk/sv (bf16 out)
    {
      MVArgs ma = {};
      ma.d[0] = {skwi, skbi, skb, L1 * D2, 1};
      ma.d[1] = {svwi, svbi, svb, L1 * D2, 1};
      ma.d[2] = {skwi, skbi, relay_k, D2, 0};  // unused (grid.y=8)
      mv_batch<<<dim3(B, 8), 128, 0, stream>>>(relay, ma);
    }
    relay_attn_partial<<<dim3(B * NH, NCH), 256, 0, stream>>>(sqv, skb, svb, mask, pm, ps, po);
    float* relay_dst = (i == NL - 1) ? (float*)d_out : relay;
    relay_finalize<<<B, 128, 0, stream>>>(pm, ps, po, so_w + wo, sobi, relay_dst);
  }
}